// Round 1
// baseline (3005.021 us; speedup 1.0000x reference)
//
#include <hip/hip_runtime.h>

typedef __bf16 bf16;
typedef __bf16 bf16x8 __attribute__((ext_vector_type(8)));
typedef float f32x4 __attribute__((ext_vector_type(4)));

#define Tt 64
#define Bb 1024
#define Dd 128
#define Ee 256
#define Hh 512
#define H3 1536

__device__ __forceinline__ float sigmf(float x) { return 1.0f / (1.0f + __expf(-x)); }

// dst[n][k] (bf16) = src[k][n] (f32); src is [K][N] row-major.
__global__ void k_transpose_bf16(const float* __restrict__ src, bf16* __restrict__ dst, int K, int N) {
    int idx = blockIdx.x * blockDim.x + threadIdx.x;
    if (idx >= K * N) return;
    int n = idx / K;
    int k = idx - n * K;
    dst[idx] = (bf16)src[(size_t)k * N + n];
}

// emb = relu(x @ W_emb + b_emb), x f32 [M][128], WT bf16 [256][128], out bf16 [M][256]
__global__ __launch_bounds__(256) void k_embed(const float* __restrict__ x, const bf16* __restrict__ WT,
                                               const float* __restrict__ bias, bf16* __restrict__ out) {
    const int lane = threadIdx.x & 63, wv = threadIdx.x >> 6;
    const int m0 = blockIdx.x * 64 + wv * 16;
    const int c0 = blockIdx.y * 64;
    const int arow = m0 + (lane & 15);
    const int koff = (lane >> 4) * 8;
    f32x4 acc[4];
#pragma unroll
    for (int s = 0; s < 4; ++s) acc[s] = f32x4{0.f, 0.f, 0.f, 0.f};

    const float* xp = x + (size_t)arow * Dd + koff;
#pragma unroll
    for (int kc = 0; kc < Dd / 32; ++kc) {
        float4 f0 = *(const float4*)(xp + kc * 32);
        float4 f1 = *(const float4*)(xp + kc * 32 + 4);
        bf16x8 a;
        a[0] = (bf16)f0.x; a[1] = (bf16)f0.y; a[2] = (bf16)f0.z; a[3] = (bf16)f0.w;
        a[4] = (bf16)f1.x; a[5] = (bf16)f1.y; a[6] = (bf16)f1.z; a[7] = (bf16)f1.w;
#pragma unroll
        for (int s = 0; s < 4; ++s) {
            int c = c0 + s * 16 + (lane & 15);
            bf16x8 b = *(const bf16x8*)(WT + (size_t)c * Dd + kc * 32 + koff);
            acc[s] = __builtin_amdgcn_mfma_f32_16x16x32_bf16(a, b, acc[s], 0, 0, 0);
        }
    }
#pragma unroll
    for (int s = 0; s < 4; ++s) {
        int col = c0 + s * 16 + (lane & 15);
        float bv = bias[col];
#pragma unroll
        for (int r = 0; r < 4; ++r) {
            int row = m0 + (lane >> 4) * 4 + r;
            float v = acc[s][r] + bv;
            out[(size_t)row * Ee + col] = (bf16)fmaxf(v, 0.0f);
        }
    }
}

// One GRU step. Aemb bf16 [B][E] (ignored if !HAS_X), hin bf16 [B][H], hf f32 [B][H] in/out,
// hout bf16 [B][H]. WihT bf16 [3H][E], WhhT bf16 [3H][H]. Gate order r,z,n.
template <int HAS_X>
__global__ __launch_bounds__(256) void k_gru_step(const bf16* __restrict__ Aemb, const bf16* __restrict__ hin,
                                                  float* __restrict__ hf, bf16* __restrict__ hout,
                                                  const bf16* __restrict__ WihT, const bf16* __restrict__ WhhT,
                                                  const float* __restrict__ b_ih, const float* __restrict__ b_hh) {
    const int lane = threadIdx.x & 63, wv = threadIdx.x >> 6;
    const int m0 = blockIdx.x * 64 + wv * 16;   // 16 batch rows per wave
    const int j0 = blockIdx.y * 32;             // 32 h-columns per block
    const int arow = m0 + (lane & 15);
    const int koff = (lane >> 4) * 8;

    f32x4 aR[2], aZ[2], aNX[2], aNH[2];
#pragma unroll
    for (int s = 0; s < 2; ++s) {
        aR[s] = f32x4{0.f, 0.f, 0.f, 0.f};
        aZ[s] = f32x4{0.f, 0.f, 0.f, 0.f};
        aNX[s] = f32x4{0.f, 0.f, 0.f, 0.f};
        aNH[s] = f32x4{0.f, 0.f, 0.f, 0.f};
    }

    if (HAS_X) {
        const bf16* ap = Aemb + (size_t)arow * Ee + koff;
#pragma unroll
        for (int kc = 0; kc < Ee / 32; ++kc) {
            bf16x8 a = *(const bf16x8*)(ap + kc * 32);
#pragma unroll
            for (int s = 0; s < 2; ++s) {
                int c = j0 + s * 16 + (lane & 15);
                const bf16* bp = WihT + (size_t)c * Ee + kc * 32 + koff;
                bf16x8 br = *(const bf16x8*)(bp);
                bf16x8 bz = *(const bf16x8*)(bp + (size_t)Hh * Ee);
                bf16x8 bn = *(const bf16x8*)(bp + (size_t)2 * Hh * Ee);
                aR[s] = __builtin_amdgcn_mfma_f32_16x16x32_bf16(a, br, aR[s], 0, 0, 0);
                aZ[s] = __builtin_amdgcn_mfma_f32_16x16x32_bf16(a, bz, aZ[s], 0, 0, 0);
                aNX[s] = __builtin_amdgcn_mfma_f32_16x16x32_bf16(a, bn, aNX[s], 0, 0, 0);
            }
        }
    }
    {
        const bf16* ap = hin + (size_t)arow * Hh + koff;
#pragma unroll
        for (int kc = 0; kc < Hh / 32; ++kc) {
            bf16x8 a = *(const bf16x8*)(ap + kc * 32);
#pragma unroll
            for (int s = 0; s < 2; ++s) {
                int c = j0 + s * 16 + (lane & 15);
                const bf16* bp = WhhT + (size_t)c * Hh + kc * 32 + koff;
                bf16x8 br = *(const bf16x8*)(bp);
                bf16x8 bz = *(const bf16x8*)(bp + (size_t)Hh * Hh);
                bf16x8 bn = *(const bf16x8*)(bp + (size_t)2 * Hh * Hh);
                aR[s] = __builtin_amdgcn_mfma_f32_16x16x32_bf16(a, br, aR[s], 0, 0, 0);
                aZ[s] = __builtin_amdgcn_mfma_f32_16x16x32_bf16(a, bz, aZ[s], 0, 0, 0);
                aNH[s] = __builtin_amdgcn_mfma_f32_16x16x32_bf16(a, bn, aNH[s], 0, 0, 0);
            }
        }
    }
#pragma unroll
    for (int s = 0; s < 2; ++s) {
        int col = j0 + s * 16 + (lane & 15);
        float bihr = b_ih[col], bhhr = b_hh[col];
        float bihz = b_ih[Hh + col], bhhz = b_hh[Hh + col];
        float bihn = b_ih[2 * Hh + col], bhhn = b_hh[2 * Hh + col];
#pragma unroll
        for (int r = 0; r < 4; ++r) {
            int row = m0 + (lane >> 4) * 4 + r;
            size_t idx = (size_t)row * Hh + col;
            float rg = sigmf(aR[s][r] + bihr + bhhr);
            float zg = sigmf(aZ[s][r] + bihz + bhhz);
            float ng = tanhf(aNX[s][r] + bihn + rg * (aNH[s][r] + bhhn));
            float ho = hf[idx];
            float hv = (1.0f - zg) * ng + zg * ho;
            hf[idx] = hv;
            hout[idx] = (bf16)hv;
        }
    }
}

// hidden = h_enc + noise  (f32 in-place), plus bf16 copy for decoder step 0.
__global__ void k_hinit(float* __restrict__ hf, const float* __restrict__ noise, bf16* __restrict__ hbf) {
    int i = blockIdx.x * blockDim.x + threadIdx.x;
    float v = hf[i] + noise[i];
    hf[i] = v;
    hbf[i] = (bf16)v;
}

// out = ys @ W_out + b_out; ys bf16 [M][512], WoutT bf16 [128][512], out f32 [M][128]
__global__ __launch_bounds__(256) void k_out(const bf16* __restrict__ ys, const bf16* __restrict__ WT,
                                             const float* __restrict__ bias, float* __restrict__ out) {
    const int lane = threadIdx.x & 63, wv = threadIdx.x >> 6;
    const int m0 = blockIdx.x * 64 + wv * 16;
    const int c0 = blockIdx.y * 64;
    const int arow = m0 + (lane & 15);
    const int koff = (lane >> 4) * 8;
    f32x4 acc[4];
#pragma unroll
    for (int s = 0; s < 4; ++s) acc[s] = f32x4{0.f, 0.f, 0.f, 0.f};

    const bf16* ap = ys + (size_t)arow * Hh + koff;
#pragma unroll
    for (int kc = 0; kc < Hh / 32; ++kc) {
        bf16x8 a = *(const bf16x8*)(ap + kc * 32);
#pragma unroll
        for (int s = 0; s < 4; ++s) {
            int c = c0 + s * 16 + (lane & 15);
            bf16x8 b = *(const bf16x8*)(WT + (size_t)c * Hh + kc * 32 + koff);
            acc[s] = __builtin_amdgcn_mfma_f32_16x16x32_bf16(a, b, acc[s], 0, 0, 0);
        }
    }
#pragma unroll
    for (int s = 0; s < 4; ++s) {
        int col = c0 + s * 16 + (lane & 15);
        float bv = bias[col];
#pragma unroll
        for (int r = 0; r < 4; ++r) {
            int row = m0 + (lane >> 4) * 4 + r;
            out[(size_t)row * Dd + col] = acc[s][r] + bv;
        }
    }
}

extern "C" void kernel_launch(void* const* d_in, const int* in_sizes, int n_in,
                              void* d_out, int out_size, void* d_ws, size_t ws_size,
                              hipStream_t stream) {
    const float* past = (const float*)d_in[0];
    const float* fut = (const float*)d_in[1];
    const float* noise = (const float*)d_in[2];
    const float* W_emb = (const float*)d_in[3];
    const float* b_emb = (const float*)d_in[4];
    const float* W_ih_enc = (const float*)d_in[5];
    const float* W_hh_enc = (const float*)d_in[6];
    const float* b_ih_enc = (const float*)d_in[7];
    const float* b_hh_enc = (const float*)d_in[8];
    const float* W_ih_dec = (const float*)d_in[9];
    const float* W_hh_dec = (const float*)d_in[10];
    const float* b_ih_dec = (const float*)d_in[11];
    const float* b_hh_dec = (const float*)d_in[12];
    const float* W_out = (const float*)d_in[13];
    const float* b_out = (const float*)d_in[14];
    float* out = (float*)d_out;

    char* w = (char*)d_ws;
    auto alloc = [&](size_t bytes) {
        char* p = w;
        w += (bytes + 255) & ~(size_t)255;
        return p;
    };
    bf16* embP = (bf16*)alloc((size_t)Tt * Bb * Ee * 2);
    bf16* embF = (bf16*)alloc((size_t)Tt * Bb * Ee * 2);
    bf16* ys = (bf16*)alloc((size_t)Tt * Bb * Hh * 2);
    float* hf = (float*)alloc((size_t)Bb * Hh * 4);
    bf16* hbfA = (bf16*)alloc((size_t)Bb * Hh * 2);
    bf16* hbfB = (bf16*)alloc((size_t)Bb * Hh * 2);
    bf16* WembT = (bf16*)alloc((size_t)Ee * Dd * 2);
    bf16* WihEncT = (bf16*)alloc((size_t)H3 * Ee * 2);
    bf16* WhhEncT = (bf16*)alloc((size_t)H3 * Hh * 2);
    bf16* WihDecT = (bf16*)alloc((size_t)H3 * Ee * 2);
    bf16* WhhDecT = (bf16*)alloc((size_t)H3 * Hh * 2);
    bf16* WoutT = (bf16*)alloc((size_t)Dd * Hh * 2);

    // Weight transposes (f32 -> bf16, [K][N] -> [N][K])
    k_transpose_bf16<<<(Dd * Ee + 255) / 256, 256, 0, stream>>>(W_emb, WembT, Dd, Ee);
    k_transpose_bf16<<<(Ee * H3 + 255) / 256, 256, 0, stream>>>(W_ih_enc, WihEncT, Ee, H3);
    k_transpose_bf16<<<(Hh * H3 + 255) / 256, 256, 0, stream>>>(W_hh_enc, WhhEncT, Hh, H3);
    k_transpose_bf16<<<(Ee * H3 + 255) / 256, 256, 0, stream>>>(W_ih_dec, WihDecT, Ee, H3);
    k_transpose_bf16<<<(Hh * H3 + 255) / 256, 256, 0, stream>>>(W_hh_dec, WhhDecT, Hh, H3);
    k_transpose_bf16<<<(Hh * Dd + 255) / 256, 256, 0, stream>>>(W_out, WoutT, Hh, Dd);

    // Embeddings (relu(x@W+b)) for past and future
    k_embed<<<dim3(Tt * Bb / 64, Ee / 64), 256, 0, stream>>>(past, WembT, b_emb, embP);
    k_embed<<<dim3(Tt * Bb / 64, Ee / 64), 256, 0, stream>>>(fut, WembT, b_emb, embF);

    // h0 = 0
    hipMemsetAsync(hf, 0, (size_t)Bb * Hh * 4, stream);
    hipMemsetAsync(hbfA, 0, (size_t)Bb * Hh * 2, stream);

    // Encoder
    for (int t = 0; t < Tt; ++t) {
        const bf16* hi = (t & 1) ? hbfB : hbfA;
        bf16* ho = (t & 1) ? hbfA : hbfB;
        k_gru_step<1><<<dim3(Bb / 64, Hh / 32), 256, 0, stream>>>(
            embP + (size_t)t * Bb * Ee, hi, hf, ho, WihEncT, WhhEncT, b_ih_enc, b_hh_enc);
    }

    // hidden = h_enc + noise
    k_hinit<<<Bb * Hh / 256, 256, 0, stream>>>(hf, noise, hbfA);

    // Decoder; ys[t] doubles as bf16 hidden-state chain
    for (int t = 0; t < Tt; ++t) {
        const bf16* hi = (t == 0) ? hbfA : ys + (size_t)(t - 1) * Bb * Hh;
        bf16* ho = ys + (size_t)t * Bb * Hh;
        if (t == 0) {
            k_gru_step<0><<<dim3(Bb / 64, Hh / 32), 256, 0, stream>>>(
                nullptr, hi, hf, ho, WihDecT, WhhDecT, b_ih_dec, b_hh_dec);
        } else {
            k_gru_step<1><<<dim3(Bb / 64, Hh / 32), 256, 0, stream>>>(
                embF + (size_t)(t - 1) * Bb * Ee, hi, hf, ho, WihDecT, WhhDecT, b_ih_dec, b_hh_dec);
        }
    }

    // Output projection
    k_out<<<dim3(Tt * Bb / 64, Dd / 64), 256, 0, stream>>>(ys, WoutT, b_out, out);
}

// Round 2
// 2735.266 us; speedup vs baseline: 1.0986x; 1.0986x over previous
//
#include <hip/hip_runtime.h>

typedef __bf16 bf16;
typedef __bf16 bf16x8 __attribute__((ext_vector_type(8)));
typedef float f32x4 __attribute__((ext_vector_type(4)));

#define Tt 64
#define Bb 1024
#define Dd 128
#define Ee 256
#define Hh 512
#define H3 1536

__device__ __forceinline__ float sigmf(float x) { return 1.0f / (1.0f + __expf(-x)); }
__device__ __forceinline__ float tanhfast(float x) {
    float e = __expf(2.0f * x);
    return 1.0f - 2.0f / (e + 1.0f);
}

// ---------------- fused weight prep: f32 [K][N] -> bf16 [N][K] for all 6 weights ----------------
__global__ void k_prep(const float* __restrict__ We, const float* __restrict__ Wie, const float* __restrict__ Whe,
                       const float* __restrict__ Wid, const float* __restrict__ Whd, const float* __restrict__ Wo,
                       bf16* __restrict__ dWe, bf16* __restrict__ dWie, bf16* __restrict__ dWhe,
                       bf16* __restrict__ dWid, bf16* __restrict__ dWhd, bf16* __restrict__ dWo) {
    long i = (long)blockIdx.x * 256 + threadIdx.x;
    const float* s;
    bf16* d;
    int K, N;
    if (i < 32768) { s = We; d = dWe; K = Dd; N = Ee; }
    else if ((i -= 32768) < 393216) { s = Wie; d = dWie; K = Ee; N = H3; }
    else if ((i -= 393216) < 786432) { s = Whe; d = dWhe; K = Hh; N = H3; }
    else if ((i -= 786432) < 393216) { s = Wid; d = dWid; K = Ee; N = H3; }
    else if ((i -= 393216) < 786432) { s = Whd; d = dWhd; K = Hh; N = H3; }
    else if ((i -= 786432) < 65536) { s = Wo; d = dWo; K = Hh; N = Dd; }
    else return;
    int n = (int)(i / K), k = (int)(i - (long)n * K);
    d[i] = (bf16)s[(size_t)k * N + n];
}

// ---------------- embed: relu(x @ W_emb + b); past (z=0) and future (z=1) fused ----------------
__global__ __launch_bounds__(256) void k_embed(const float* __restrict__ xP, const float* __restrict__ xF,
                                               const bf16* __restrict__ WT, const float* __restrict__ bias,
                                               bf16* __restrict__ oP, bf16* __restrict__ oF) {
    const int lane = threadIdx.x & 63, wv = threadIdx.x >> 6;
    const float* x = blockIdx.z ? xF : xP;
    bf16* o = blockIdx.z ? oF : oP;
    const int m0w = blockIdx.x * 128 + wv * 32;
    const int c0 = blockIdx.y * 64;
    const int koff = (lane >> 4) * 8;
    f32x4 acc[2][4];
#pragma unroll
    for (int m = 0; m < 2; ++m)
#pragma unroll
        for (int s = 0; s < 4; ++s) acc[m][s] = f32x4{0.f, 0.f, 0.f, 0.f};

    const float* xp0 = x + (size_t)(m0w + (lane & 15)) * Dd + koff;
#pragma unroll
    for (int kc = 0; kc < 4; ++kc) {
        bf16x8 a0, a1;
        {
            float4 f0 = *(const float4*)(xp0 + kc * 32);
            float4 f1 = *(const float4*)(xp0 + kc * 32 + 4);
            a0[0] = (bf16)f0.x; a0[1] = (bf16)f0.y; a0[2] = (bf16)f0.z; a0[3] = (bf16)f0.w;
            a0[4] = (bf16)f1.x; a0[5] = (bf16)f1.y; a0[6] = (bf16)f1.z; a0[7] = (bf16)f1.w;
            float4 g0 = *(const float4*)(xp0 + 16 * Dd + kc * 32);
            float4 g1 = *(const float4*)(xp0 + 16 * Dd + kc * 32 + 4);
            a1[0] = (bf16)g0.x; a1[1] = (bf16)g0.y; a1[2] = (bf16)g0.z; a1[3] = (bf16)g0.w;
            a1[4] = (bf16)g1.x; a1[5] = (bf16)g1.y; a1[6] = (bf16)g1.z; a1[7] = (bf16)g1.w;
        }
#pragma unroll
        for (int s = 0; s < 4; ++s) {
            bf16x8 b = *(const bf16x8*)(WT + (size_t)(c0 + s * 16 + (lane & 15)) * Dd + kc * 32 + koff);
            acc[0][s] = __builtin_amdgcn_mfma_f32_16x16x32_bf16(a0, b, acc[0][s], 0, 0, 0);
            acc[1][s] = __builtin_amdgcn_mfma_f32_16x16x32_bf16(a1, b, acc[1][s], 0, 0, 0);
        }
    }
#pragma unroll
    for (int m = 0; m < 2; ++m)
#pragma unroll
        for (int s = 0; s < 4; ++s) {
            int col = c0 + s * 16 + (lane & 15);
            float bv = bias[col];
#pragma unroll
            for (int r = 0; r < 4; ++r) {
                int row = m0w + m * 16 + (lane >> 4) * 4 + r;
                o[(size_t)row * Ee + col] = (bf16)fmaxf(acc[m][s][r] + bv, 0.0f);
            }
        }
}

// ---------------- persistent cooperative GRU (encoder + noise + decoder) ----------------
// grid 256 = 16 batch-groups (im) x 16 col-blocks (in). Block slice: rows [im*64,+64), h-cols [in*32,+32).
// Weights in LDS in fragment order [s][kc][lane][8bf16]; h f32 carried in registers.
__global__ __launch_bounds__(256, 1) void k_gru_all(
    const bf16* __restrict__ embP, const bf16* __restrict__ embF, const float* __restrict__ noise,
    const bf16* __restrict__ WihE, const bf16* __restrict__ WhhE,
    const float* __restrict__ bIhE, const float* __restrict__ bHhE,
    const bf16* __restrict__ WihD, const bf16* __restrict__ WhhD,
    const float* __restrict__ bIhD, const float* __restrict__ bHhD,
    bf16* __restrict__ hA, bf16* __restrict__ hB, bf16* __restrict__ ys, unsigned* __restrict__ ctrs) {
    __shared__ bf16 Wih[6 * 8 * 64 * 8];    // 49152 B
    __shared__ bf16 Whh[6 * 16 * 64 * 8];   // 98304 B
    const int tid = threadIdx.x;
    const int lane = tid & 63, wv = tid >> 6;
    const int bid = blockIdx.x;
    const int im = bid >> 4;   // batch group 0..15 (consecutive bids per group: dispatch-order safe)
    const int in = bid & 15;   // column block 0..15
    const int m0 = im * 64 + wv * 16;
    const int j0 = in * 32;
    const int arow = m0 + (lane & 15);
    const int koff = (lane >> 4) * 8;
    unsigned* ctr = ctrs + (size_t)im * 64;  // one 256B line per group

    const bf16x8* WihV = (const bf16x8*)Wih;
    const bf16x8* WhhV = (const bf16x8*)Whh;

    auto stage = [&](const bf16* WT, int Kdim, int KC, bf16* lds) {
        int total = 6 * KC * 64;
        for (int idx = tid; idx < total; idx += 256) {
            int ln = idx & 63;
            int kc = (idx >> 6) % KC;
            int s = (idx >> 6) / KC;
            int gate = s >> 1, f = s & 1;
            int col = gate * Hh + j0 + f * 16 + (ln & 15);
            int k = kc * 32 + (ln >> 4) * 8;
            *(bf16x8*)(lds + (size_t)idx * 8) = *(const bf16x8*)(WT + (size_t)col * Kdim + k);
        }
    };

    float bi[6], bh[6];
    auto load_bias = [&](const float* bIh, const float* bHh) {
#pragma unroll
        for (int g = 0; g < 3; ++g)
#pragma unroll
            for (int f = 0; f < 2; ++f) {
                int c = g * Hh + j0 + f * 16 + (lane & 15);
                bi[g * 2 + f] = bIh[c];
                bh[g * 2 + f] = bHh[c];
            }
    };

    auto group_barrier = [&](unsigned target) {
        __syncthreads();
        if (tid == 0) {
            __threadfence();  // release: push h writes past XCD L2
            atomicAdd(ctr, 1u);
            while (__hip_atomic_load(ctr, __ATOMIC_RELAXED, __HIP_MEMORY_SCOPE_AGENT) < target)
                __builtin_amdgcn_s_sleep(2);
            __threadfence();  // acquire: invalidate stale L1/L2 lines
        }
        __syncthreads();
    };

    float hreg[8];
#pragma unroll
    for (int i = 0; i < 8; ++i) hreg[i] = 0.0f;

    // One GRU step for this block's slice. xp/hp may be nullptr (skip phase).
    auto do_step = [&](const bf16* xp, const bf16* hp, bf16* op) {
        f32x4 aR[2], aZ[2], aNX[2], aNH[2];
#pragma unroll
        for (int f = 0; f < 2; ++f) {
            aR[f] = f32x4{0.f, 0.f, 0.f, 0.f};
            aZ[f] = f32x4{0.f, 0.f, 0.f, 0.f};
            aNX[f] = f32x4{0.f, 0.f, 0.f, 0.f};
            aNH[f] = f32x4{0.f, 0.f, 0.f, 0.f};
        }
        if (xp) {
            const bf16* ap = xp + (size_t)arow * Ee + koff;
#pragma unroll
            for (int kc = 0; kc < 8; ++kc) {
                bf16x8 a = *(const bf16x8*)(ap + kc * 32);
#pragma unroll
                for (int f = 0; f < 2; ++f) {
                    aR[f] = __builtin_amdgcn_mfma_f32_16x16x32_bf16(a, WihV[((0 + f) * 8 + kc) * 64 + lane], aR[f], 0, 0, 0);
                    aZ[f] = __builtin_amdgcn_mfma_f32_16x16x32_bf16(a, WihV[((2 + f) * 8 + kc) * 64 + lane], aZ[f], 0, 0, 0);
                    aNX[f] = __builtin_amdgcn_mfma_f32_16x16x32_bf16(a, WihV[((4 + f) * 8 + kc) * 64 + lane], aNX[f], 0, 0, 0);
                }
            }
        }
        if (hp) {
            const bf16* ap = hp + (size_t)arow * Hh + koff;
#pragma unroll
            for (int kc = 0; kc < 16; ++kc) {
                bf16x8 a = *(const bf16x8*)(ap + kc * 32);
#pragma unroll
                for (int f = 0; f < 2; ++f) {
                    aR[f] = __builtin_amdgcn_mfma_f32_16x16x32_bf16(a, WhhV[((0 + f) * 16 + kc) * 64 + lane], aR[f], 0, 0, 0);
                    aZ[f] = __builtin_amdgcn_mfma_f32_16x16x32_bf16(a, WhhV[((2 + f) * 16 + kc) * 64 + lane], aZ[f], 0, 0, 0);
                    aNH[f] = __builtin_amdgcn_mfma_f32_16x16x32_bf16(a, WhhV[((4 + f) * 16 + kc) * 64 + lane], aNH[f], 0, 0, 0);
                }
            }
        }
#pragma unroll
        for (int f = 0; f < 2; ++f) {
            int col = j0 + f * 16 + (lane & 15);
#pragma unroll
            for (int r = 0; r < 4; ++r) {
                int row = m0 + (lane >> 4) * 4 + r;
                float rg = sigmf(aR[f][r] + bi[0 + f] + bh[0 + f]);
                float zg = sigmf(aZ[f][r] + bi[2 + f] + bh[2 + f]);
                float ng = tanhfast(aNX[f][r] + bi[4 + f] + rg * (aNH[f][r] + bh[4 + f]));
                float hv = (1.0f - zg) * ng + zg * hreg[f * 4 + r];
                hreg[f * 4 + r] = hv;
                op[(size_t)row * Hh + col] = (bf16)hv;
            }
        }
    };

    // Note: bias index layout: bi[g*2+f] -> bi[0+f]=r, bi[2+f]=z, bi[4+f]=n. (g*2+f with g=0,1,2)

    // ---------- encoder ----------
    stage(WihE, Ee, 8, Wih);
    stage(WhhE, Hh, 16, Whh);
    load_bias(bIhE, bHhE);
    __syncthreads();

    const bf16* hprev = nullptr;
#pragma unroll 1
    for (int t = 0; t < Tt; ++t) {
        bf16* hout = (t & 1) ? hB : hA;
        do_step(embP + (size_t)t * Bb * Ee, hprev, hout);
        group_barrier(16u * (t + 1));
        hprev = hout;
    }

    // ---------- hidden = h_enc + noise; switch to decoder weights ----------
#pragma unroll
    for (int f = 0; f < 2; ++f) {
        int col = j0 + f * 16 + (lane & 15);
#pragma unroll
        for (int r = 0; r < 4; ++r) {
            int row = m0 + (lane >> 4) * 4 + r;
            float v = hreg[f * 4 + r] + noise[(size_t)row * Hh + col];
            hreg[f * 4 + r] = v;
            hA[(size_t)row * Hh + col] = (bf16)v;
        }
    }
    __syncthreads();  // all waves done with encoder LDS reads
    stage(WihD, Ee, 8, Wih);
    stage(WhhD, Hh, 16, Whh);
    load_bias(bIhD, bHhD);
    group_barrier(16u * 65);  // hidden visible to group + LDS staged

    // ---------- decoder ----------
#pragma unroll 1
    for (int t = 0; t < Tt; ++t) {
        const bf16* xp = t ? (embF + (size_t)(t - 1) * Bb * Ee) : nullptr;
        const bf16* hp = t ? (ys + (size_t)(t - 1) * Bb * Hh) : hA;
        bf16* op = ys + (size_t)t * Bb * Hh;
        do_step(xp, hp, op);
        if (t < Tt - 1) group_barrier(16u * (66 + t));
    }
}

// ---------------- out = ys @ W_out + b_out ----------------
__global__ __launch_bounds__(256) void k_out(const bf16* __restrict__ ys, const bf16* __restrict__ WT,
                                             const float* __restrict__ bias, float* __restrict__ out) {
    const int lane = threadIdx.x & 63, wv = threadIdx.x >> 6;
    const int m0w = blockIdx.x * 128 + wv * 32;
    const int c0 = blockIdx.y * 64;
    const int koff = (lane >> 4) * 8;
    f32x4 acc[2][4];
#pragma unroll
    for (int m = 0; m < 2; ++m)
#pragma unroll
        for (int s = 0; s < 4; ++s) acc[m][s] = f32x4{0.f, 0.f, 0.f, 0.f};

    const bf16* a0p = ys + (size_t)(m0w + (lane & 15)) * Hh + koff;
#pragma unroll
    for (int kc = 0; kc < 16; ++kc) {
        bf16x8 a0 = *(const bf16x8*)(a0p + kc * 32);
        bf16x8 a1 = *(const bf16x8*)(a0p + 16 * Hh + kc * 32);
#pragma unroll
        for (int s = 0; s < 4; ++s) {
            bf16x8 b = *(const bf16x8*)(WT + (size_t)(c0 + s * 16 + (lane & 15)) * Hh + kc * 32 + koff);
            acc[0][s] = __builtin_amdgcn_mfma_f32_16x16x32_bf16(a0, b, acc[0][s], 0, 0, 0);
            acc[1][s] = __builtin_amdgcn_mfma_f32_16x16x32_bf16(a1, b, acc[1][s], 0, 0, 0);
        }
    }
#pragma unroll
    for (int m = 0; m < 2; ++m)
#pragma unroll
        for (int s = 0; s < 4; ++s) {
            int col = c0 + s * 16 + (lane & 15);
            float bv = bias[col];
#pragma unroll
            for (int r = 0; r < 4; ++r) {
                int row = m0w + m * 16 + (lane >> 4) * 4 + r;
                out[(size_t)row * Dd + col] = acc[m][s][r] + bv;
            }
        }
}

extern "C" void kernel_launch(void* const* d_in, const int* in_sizes, int n_in,
                              void* d_out, int out_size, void* d_ws, size_t ws_size,
                              hipStream_t stream) {
    const float* past = (const float*)d_in[0];
    const float* fut = (const float*)d_in[1];
    const float* noise = (const float*)d_in[2];
    const float* W_emb = (const float*)d_in[3];
    const float* b_emb = (const float*)d_in[4];
    const float* W_ih_enc = (const float*)d_in[5];
    const float* W_hh_enc = (const float*)d_in[6];
    const float* b_ih_enc = (const float*)d_in[7];
    const float* b_hh_enc = (const float*)d_in[8];
    const float* W_ih_dec = (const float*)d_in[9];
    const float* W_hh_dec = (const float*)d_in[10];
    const float* b_ih_dec = (const float*)d_in[11];
    const float* b_hh_dec = (const float*)d_in[12];
    const float* W_out = (const float*)d_in[13];
    const float* b_out = (const float*)d_in[14];
    float* out = (float*)d_out;

    char* w = (char*)d_ws;
    auto alloc = [&](size_t bytes) {
        char* p = w;
        w += (bytes + 255) & ~(size_t)255;
        return p;
    };
    bf16* embP = (bf16*)alloc((size_t)Tt * Bb * Ee * 2);
    bf16* embF = (bf16*)alloc((size_t)Tt * Bb * Ee * 2);
    bf16* ys = (bf16*)alloc((size_t)Tt * Bb * Hh * 2);
    bf16* hA = (bf16*)alloc((size_t)Bb * Hh * 2);
    bf16* hB = (bf16*)alloc((size_t)Bb * Hh * 2);
    bf16* WembT = (bf16*)alloc((size_t)Ee * Dd * 2);
    bf16* WihEncT = (bf16*)alloc((size_t)H3 * Ee * 2);
    bf16* WhhEncT = (bf16*)alloc((size_t)H3 * Hh * 2);
    bf16* WihDecT = (bf16*)alloc((size_t)H3 * Ee * 2);
    bf16* WhhDecT = (bf16*)alloc((size_t)H3 * Hh * 2);
    bf16* WoutT = (bf16*)alloc((size_t)Dd * Hh * 2);
    unsigned* ctrs = (unsigned*)alloc(16 * 64 * sizeof(unsigned));

    // weight prep (all six transposes fused): total 2457600 elements
    k_prep<<<9600, 256, 0, stream>>>(W_emb, W_ih_enc, W_hh_enc, W_ih_dec, W_hh_dec, W_out,
                                     WembT, WihEncT, WhhEncT, WihDecT, WhhDecT, WoutT);

    // embeddings (past + future fused)
    k_embed<<<dim3(Tt * Bb / 128, Ee / 64, 2), 256, 0, stream>>>(past, fut, WembT, b_emb, embP, embF);

    // reset group barrier counters (monotonic per launch)
    hipMemsetAsync(ctrs, 0, 16 * 64 * sizeof(unsigned), stream);

    // cooperative persistent recurrent kernel
    void* args[] = {(void*)&embP, (void*)&embF, (void*)&noise,
                    (void*)&WihEncT, (void*)&WhhEncT, (void*)&b_ih_enc, (void*)&b_hh_enc,
                    (void*)&WihDecT, (void*)&WhhDecT, (void*)&b_ih_dec, (void*)&b_hh_dec,
                    (void*)&hA, (void*)&hB, (void*)&ys, (void*)&ctrs};
    hipLaunchCooperativeKernel((const void*)k_gru_all, dim3(256), dim3(256), args, 0, stream);

    // output projection
    k_out<<<dim3(Tt * Bb / 128, Dd / 64), 256, 0, stream>>>(ys, WoutT, b_out, out);
}

// Round 3
// 1226.206 us; speedup vs baseline: 2.4507x; 2.2307x over previous
//
#include <hip/hip_runtime.h>

typedef __bf16 bf16;
typedef __bf16 bf16x8 __attribute__((ext_vector_type(8)));
typedef float f32x4 __attribute__((ext_vector_type(4)));

#define Tt 64
#define Bb 1024
#define Dd 128
#define Ee 256
#define Hh 512
#define H3 1536

__device__ __forceinline__ float sigmf(float x) { return 1.0f / (1.0f + __expf(-x)); }
__device__ __forceinline__ float tanhfast(float x) {
    float e = __expf(2.0f * x);
    return 1.0f - 2.0f / (e + 1.0f);
}

// Cache-bypassing (device-coherent) 16B load / 2B store: sc0 sc1 flags reach the
// coherence point without any wbl2/inv of the whole cache.
#define LD_SC(dst, bp, OFF) \
    asm volatile("global_load_dwordx4 %0, %1, off offset:" #OFF " sc0 sc1" : "=v"(dst) : "v"(bp))
#define ST_SC(bp, OFF, val) \
    asm volatile("global_store_short %0, %1, off offset:" #OFF " sc0 sc1" :: "v"(bp), "v"(val))
#define LDROW16(arr, bp) \
    LD_SC(arr[0], bp, 0);    LD_SC(arr[1], bp, 64);   LD_SC(arr[2], bp, 128);  LD_SC(arr[3], bp, 192);  \
    LD_SC(arr[4], bp, 256);  LD_SC(arr[5], bp, 320);  LD_SC(arr[6], bp, 384);  LD_SC(arr[7], bp, 448);  \
    LD_SC(arr[8], bp, 512);  LD_SC(arr[9], bp, 576);  LD_SC(arr[10], bp, 640); LD_SC(arr[11], bp, 704); \
    LD_SC(arr[12], bp, 768); LD_SC(arr[13], bp, 832); LD_SC(arr[14], bp, 896); LD_SC(arr[15], bp, 960);

// ---------------- fused weight prep: f32 [K][N] -> bf16 [N][K] for all 6 weights ----------------
__global__ void k_prep(const float* __restrict__ We, const float* __restrict__ Wie, const float* __restrict__ Whe,
                       const float* __restrict__ Wid, const float* __restrict__ Whd, const float* __restrict__ Wo,
                       bf16* __restrict__ dWe, bf16* __restrict__ dWie, bf16* __restrict__ dWhe,
                       bf16* __restrict__ dWid, bf16* __restrict__ dWhd, bf16* __restrict__ dWo) {
    long i = (long)blockIdx.x * 256 + threadIdx.x;
    const float* s;
    bf16* d;
    int K, N;
    if (i < 32768) { s = We; d = dWe; K = Dd; N = Ee; }
    else if ((i -= 32768) < 393216) { s = Wie; d = dWie; K = Ee; N = H3; }
    else if ((i -= 393216) < 786432) { s = Whe; d = dWhe; K = Hh; N = H3; }
    else if ((i -= 786432) < 393216) { s = Wid; d = dWid; K = Ee; N = H3; }
    else if ((i -= 393216) < 786432) { s = Whd; d = dWhd; K = Hh; N = H3; }
    else if ((i -= 786432) < 65536) { s = Wo; d = dWo; K = Hh; N = Dd; }
    else return;
    int n = (int)(i / K), k = (int)(i - (long)n * K);
    d[i] = (bf16)s[(size_t)k * N + n];
}

// ---------------- embed: relu(x @ W_emb + b); past (z=0) and future (z=1) fused ----------------
__global__ __launch_bounds__(256) void k_embed(const float* __restrict__ xP, const float* __restrict__ xF,
                                               const bf16* __restrict__ WT, const float* __restrict__ bias,
                                               bf16* __restrict__ oP, bf16* __restrict__ oF) {
    const int lane = threadIdx.x & 63, wv = threadIdx.x >> 6;
    const float* x = blockIdx.z ? xF : xP;
    bf16* o = blockIdx.z ? oF : oP;
    const int m0w = blockIdx.x * 128 + wv * 32;
    const int c0 = blockIdx.y * 64;
    const int koff = (lane >> 4) * 8;
    f32x4 acc[2][4];
#pragma unroll
    for (int m = 0; m < 2; ++m)
#pragma unroll
        for (int s = 0; s < 4; ++s) acc[m][s] = f32x4{0.f, 0.f, 0.f, 0.f};

    const float* xp0 = x + (size_t)(m0w + (lane & 15)) * Dd + koff;
#pragma unroll
    for (int kc = 0; kc < 4; ++kc) {
        bf16x8 a0, a1;
        {
            float4 f0 = *(const float4*)(xp0 + kc * 32);
            float4 f1 = *(const float4*)(xp0 + kc * 32 + 4);
            a0[0] = (bf16)f0.x; a0[1] = (bf16)f0.y; a0[2] = (bf16)f0.z; a0[3] = (bf16)f0.w;
            a0[4] = (bf16)f1.x; a0[5] = (bf16)f1.y; a0[6] = (bf16)f1.z; a0[7] = (bf16)f1.w;
            float4 g0 = *(const float4*)(xp0 + 16 * Dd + kc * 32);
            float4 g1 = *(const float4*)(xp0 + 16 * Dd + kc * 32 + 4);
            a1[0] = (bf16)g0.x; a1[1] = (bf16)g0.y; a1[2] = (bf16)g0.z; a1[3] = (bf16)g0.w;
            a1[4] = (bf16)g1.x; a1[5] = (bf16)g1.y; a1[6] = (bf16)g1.z; a1[7] = (bf16)g1.w;
        }
#pragma unroll
        for (int s = 0; s < 4; ++s) {
            bf16x8 b = *(const bf16x8*)(WT + (size_t)(c0 + s * 16 + (lane & 15)) * Dd + kc * 32 + koff);
            acc[0][s] = __builtin_amdgcn_mfma_f32_16x16x32_bf16(a0, b, acc[0][s], 0, 0, 0);
            acc[1][s] = __builtin_amdgcn_mfma_f32_16x16x32_bf16(a1, b, acc[1][s], 0, 0, 0);
        }
    }
#pragma unroll
    for (int m = 0; m < 2; ++m)
#pragma unroll
        for (int s = 0; s < 4; ++s) {
            int col = c0 + s * 16 + (lane & 15);
            float bv = bias[col];
#pragma unroll
            for (int r = 0; r < 4; ++r) {
                int row = m0w + m * 16 + (lane >> 4) * 4 + r;
                o[(size_t)row * Ee + col] = (bf16)fmaxf(acc[m][s][r] + bv, 0.0f);
            }
        }
}

// ---------------- persistent cooperative GRU (encoder + noise + decoder) ----------------
// grid 256 = 16 batch-groups (im) x 16 col-blocks (in). Block slice: rows [im*64,+64), h-cols [in*32,+32).
// Wave tiling: wv -> (rh = wv>>1: 32-row half, ch = wv&1: 16-col half). B-frags from LDS (reused 2x),
// h A-frags via sc0/sc1 global loads, x A-frags via cached loads (pipelined before the flag wait).
__global__ __launch_bounds__(256, 1) void k_gru_all(
    const bf16* __restrict__ embP, const bf16* __restrict__ embF, const float* __restrict__ noise,
    const bf16* __restrict__ WihE, const bf16* __restrict__ WhhE,
    const float* __restrict__ bIhE, const float* __restrict__ bHhE,
    const bf16* __restrict__ WihD, const bf16* __restrict__ WhhD,
    const float* __restrict__ bIhD, const float* __restrict__ bHhD,
    bf16* __restrict__ hA, bf16* __restrict__ hB, bf16* __restrict__ ys, unsigned* __restrict__ ctrs) {
    __shared__ bf16 Wih[6 * 8 * 64 * 8];    // 49152 B
    __shared__ bf16 Whh[6 * 16 * 64 * 8];   // 98304 B
    const int tid = threadIdx.x;
    const int lane = tid & 63, wv = tid >> 6;
    const int im = blockIdx.x >> 4;  // batch group 0..15
    const int in = blockIdx.x & 15;  // column block 0..15
    const int rh = wv >> 1, ch = wv & 1;
    const int rowb = im * 64 + rh * 32;       // wave's 32 rows start
    const int arow0 = rowb + (lane & 15);     // A row for rowfrag 0
    const int koff = (lane >> 4) * 8;
    const int colc = in * 32 + ch * 16 + (lane & 15);  // this lane's output column
    unsigned* ctr = ctrs + (size_t)im * 64;

    const bf16x8* WihV = (const bf16x8*)Wih;
    const bf16x8* WhhV = (const bf16x8*)Whh;

    auto stage = [&](const bf16* WT, int Kdim, int KC, bf16* lds) {
        int total = 6 * KC * 64;
        for (int idx = tid; idx < total; idx += 256) {
            int ln = idx & 63;
            int kc = (idx >> 6) % KC;
            int s = (idx >> 6) / KC;
            int gate = s >> 1, f = s & 1;
            int col = gate * Hh + in * 32 + f * 16 + (ln & 15);
            int k = kc * 32 + (ln >> 4) * 8;
            *(bf16x8*)(lds + (size_t)idx * 8) = *(const bf16x8*)(WT + (size_t)col * Kdim + k);
        }
    };

    float bi[3], bh[3];
    auto load_bias = [&](const float* bIh, const float* bHh) {
#pragma unroll
        for (int g = 0; g < 3; ++g) {
            bi[g] = bIh[g * Hh + colc];
            bh[g] = bHh[g * Hh + colc];
        }
    };

    // release: all this wave's sc stores done -> block barrier -> one add per block
    auto signal = [&]() {
        asm volatile("s_waitcnt vmcnt(0)" ::: "memory");
        __syncthreads();
        if (tid == 0) atomicAdd(ctr, 1u);
    };
    // acquire: every lane polls (uniform value, single broadcast load); no extra barrier
    auto wait_for = [&](unsigned target) {
        while (__hip_atomic_load(ctr, __ATOMIC_RELAXED, __HIP_MEMORY_SCOPE_AGENT) < target)
            __builtin_amdgcn_s_sleep(1);
    };

    f32x4 aR[2], aZ[2], aNX[2], aNH[2];
    auto zacc = [&]() {
#pragma unroll
        for (int i = 0; i < 2; ++i) {
            aR[i] = f32x4{0.f, 0.f, 0.f, 0.f};
            aZ[i] = f32x4{0.f, 0.f, 0.f, 0.f};
            aNX[i] = f32x4{0.f, 0.f, 0.f, 0.f};
            aNH[i] = f32x4{0.f, 0.f, 0.f, 0.f};
        }
    };

    auto xp_phase = [&](const bf16* xp) {
        const bf16* a0p = xp + (size_t)arow0 * Ee + koff;
#pragma unroll
        for (int kc = 0; kc < 8; ++kc) {
            bf16x8 a0 = *(const bf16x8*)(a0p + kc * 32);
            bf16x8 a1 = *(const bf16x8*)(a0p + 16 * Ee + kc * 32);
            bf16x8 br = WihV[((0 + ch) * 8 + kc) * 64 + lane];
            bf16x8 bz = WihV[((2 + ch) * 8 + kc) * 64 + lane];
            bf16x8 bn = WihV[((4 + ch) * 8 + kc) * 64 + lane];
            aR[0] = __builtin_amdgcn_mfma_f32_16x16x32_bf16(a0, br, aR[0], 0, 0, 0);
            aR[1] = __builtin_amdgcn_mfma_f32_16x16x32_bf16(a1, br, aR[1], 0, 0, 0);
            aZ[0] = __builtin_amdgcn_mfma_f32_16x16x32_bf16(a0, bz, aZ[0], 0, 0, 0);
            aZ[1] = __builtin_amdgcn_mfma_f32_16x16x32_bf16(a1, bz, aZ[1], 0, 0, 0);
            aNX[0] = __builtin_amdgcn_mfma_f32_16x16x32_bf16(a0, bn, aNX[0], 0, 0, 0);
            aNX[1] = __builtin_amdgcn_mfma_f32_16x16x32_bf16(a1, bn, aNX[1], 0, 0, 0);
        }
    };

    auto hw_phase = [&](const bf16* hp) {
        const bf16* h0p = hp + (size_t)arow0 * Hh + koff;
        const bf16* h1p = h0p + 16 * Hh;
        bf16x8 h0[16], h1[16];
        LDROW16(h0, h0p);
        LDROW16(h1, h1p);
        asm volatile("s_waitcnt vmcnt(0)" ::: "memory");
        __builtin_amdgcn_sched_barrier(0);
#pragma unroll
        for (int kc = 0; kc < 16; ++kc) {
            bf16x8 br = WhhV[((0 + ch) * 16 + kc) * 64 + lane];
            bf16x8 bz = WhhV[((2 + ch) * 16 + kc) * 64 + lane];
            bf16x8 bn = WhhV[((4 + ch) * 16 + kc) * 64 + lane];
            aR[0] = __builtin_amdgcn_mfma_f32_16x16x32_bf16(h0[kc], br, aR[0], 0, 0, 0);
            aR[1] = __builtin_amdgcn_mfma_f32_16x16x32_bf16(h1[kc], br, aR[1], 0, 0, 0);
            aZ[0] = __builtin_amdgcn_mfma_f32_16x16x32_bf16(h0[kc], bz, aZ[0], 0, 0, 0);
            aZ[1] = __builtin_amdgcn_mfma_f32_16x16x32_bf16(h1[kc], bz, aZ[1], 0, 0, 0);
            aNH[0] = __builtin_amdgcn_mfma_f32_16x16x32_bf16(h0[kc], bn, aNH[0], 0, 0, 0);
            aNH[1] = __builtin_amdgcn_mfma_f32_16x16x32_bf16(h1[kc], bn, aNH[1], 0, 0, 0);
        }
    };

    float hreg[8];
#pragma unroll
    for (int i = 0; i < 8; ++i) hreg[i] = 0.0f;

    auto epi = [&](bf16* op) {
#pragma unroll
        for (int rf = 0; rf < 2; ++rf) {
            bf16* stb = op + (size_t)(rowb + rf * 16 + (lane >> 4) * 4) * Hh + colc;
            unsigned short us[4];
#pragma unroll
            for (int r = 0; r < 4; ++r) {
                float rg = sigmf(aR[rf][r] + bi[0] + bh[0]);
                float zg = sigmf(aZ[rf][r] + bi[1] + bh[1]);
                float ng = tanhfast(aNX[rf][r] + bi[2] + rg * (aNH[rf][r] + bh[2]));
                float hv = (1.0f - zg) * ng + zg * hreg[rf * 4 + r];
                hreg[rf * 4 + r] = hv;
                us[r] = __builtin_bit_cast(unsigned short, (bf16)hv);
            }
            ST_SC(stb, 0, us[0]);
            ST_SC(stb, 1024, us[1]);
            ST_SC(stb, 2048, us[2]);
            ST_SC(stb, 3072, us[3]);
        }
    };

    // ---------- encoder ----------
    stage(WihE, Ee, 8, Wih);
    stage(WhhE, Hh, 16, Whh);
    load_bias(bIhE, bHhE);
    __syncthreads();

#pragma unroll 1
    for (int t = 0; t < Tt; ++t) {
        zacc();
        xp_phase(embP + (size_t)t * Bb * Ee);
        if (t > 0) {
            wait_for(16u * t);
            hw_phase(((t - 1) & 1) ? hB : hA);
        }
        epi((t & 1) ? hB : hA);
        signal();  // count -> 16*(t+1)
    }

    // ---------- hidden = h_enc + noise; switch to decoder weights ----------
    wait_for(16u * Tt);  // all peers finished READING hA/hB for step Tt-1
    {
#pragma unroll
        for (int rf = 0; rf < 2; ++rf) {
            bf16* stb = hA + (size_t)(rowb + rf * 16 + (lane >> 4) * 4) * Hh + colc;
            unsigned short us[4];
#pragma unroll
            for (int r = 0; r < 4; ++r) {
                int row = rowb + rf * 16 + (lane >> 4) * 4 + r;
                float v = hreg[rf * 4 + r] + noise[(size_t)row * Hh + colc];
                hreg[rf * 4 + r] = v;
                us[r] = __builtin_bit_cast(unsigned short, (bf16)v);
            }
            ST_SC(stb, 0, us[0]);
            ST_SC(stb, 1024, us[1]);
            ST_SC(stb, 2048, us[2]);
            ST_SC(stb, 3072, us[3]);
        }
    }
    stage(WihD, Ee, 8, Wih);
    stage(WhhD, Hh, 16, Whh);
    load_bias(bIhD, bHhD);
    signal();               // count -> 16*(Tt+1); also publishes hA stores + LDS staging
    wait_for(16u * (Tt + 1));

    // ---------- decoder; ys[t] doubles as the bf16 hidden chain ----------
#pragma unroll 1
    for (int t = 0; t < Tt; ++t) {
        zacc();
        if (t > 0) {
            xp_phase(embF + (size_t)(t - 1) * Bb * Ee);
            wait_for(16u * (Tt + 1 + t));
        }
        hw_phase(t ? ys + (size_t)(t - 1) * Bb * Hh : hA);
        epi(ys + (size_t)t * Bb * Hh);
        if (t < Tt - 1) signal();  // count -> 16*(Tt+2+t)
    }
}

// ---------------- out = ys @ W_out + b_out; 64 rows/wave ----------------
__global__ __launch_bounds__(256) void k_out(const bf16* __restrict__ ys, const bf16* __restrict__ WT,
                                             const float* __restrict__ bias, float* __restrict__ out) {
    const int lane = threadIdx.x & 63, wv = threadIdx.x >> 6;
    const int m0w = blockIdx.x * 256 + wv * 64;
    const int c0 = blockIdx.y * 64;
    const int koff = (lane >> 4) * 8;
    f32x4 acc[4][4];
#pragma unroll
    for (int m = 0; m < 4; ++m)
#pragma unroll
        for (int s = 0; s < 4; ++s) acc[m][s] = f32x4{0.f, 0.f, 0.f, 0.f};

    const bf16* ap = ys + (size_t)(m0w + (lane & 15)) * Hh + koff;
#pragma unroll
    for (int kc = 0; kc < 16; ++kc) {
        bf16x8 a0 = *(const bf16x8*)(ap + kc * 32);
        bf16x8 a1 = *(const bf16x8*)(ap + 16 * Hh + kc * 32);
        bf16x8 a2 = *(const bf16x8*)(ap + 32 * Hh + kc * 32);
        bf16x8 a3 = *(const bf16x8*)(ap + 48 * Hh + kc * 32);
#pragma unroll
        for (int s = 0; s < 4; ++s) {
            bf16x8 b = *(const bf16x8*)(WT + (size_t)(c0 + s * 16 + (lane & 15)) * Hh + kc * 32 + koff);
            acc[0][s] = __builtin_amdgcn_mfma_f32_16x16x32_bf16(a0, b, acc[0][s], 0, 0, 0);
            acc[1][s] = __builtin_amdgcn_mfma_f32_16x16x32_bf16(a1, b, acc[1][s], 0, 0, 0);
            acc[2][s] = __builtin_amdgcn_mfma_f32_16x16x32_bf16(a2, b, acc[2][s], 0, 0, 0);
            acc[3][s] = __builtin_amdgcn_mfma_f32_16x16x32_bf16(a3, b, acc[3][s], 0, 0, 0);
        }
    }
#pragma unroll
    for (int m = 0; m < 4; ++m)
#pragma unroll
        for (int s = 0; s < 4; ++s) {
            int col = c0 + s * 16 + (lane & 15);
            float bv = bias[col];
#pragma unroll
            for (int r = 0; r < 4; ++r) {
                int row = m0w + m * 16 + (lane >> 4) * 4 + r;
                out[(size_t)row * Dd + col] = acc[m][s][r] + bv;
            }
        }
}

extern "C" void kernel_launch(void* const* d_in, const int* in_sizes, int n_in,
                              void* d_out, int out_size, void* d_ws, size_t ws_size,
                              hipStream_t stream) {
    const float* past = (const float*)d_in[0];
    const float* fut = (const float*)d_in[1];
    const float* noise = (const float*)d_in[2];
    const float* W_emb = (const float*)d_in[3];
    const float* b_emb = (const float*)d_in[4];
    const float* W_ih_enc = (const float*)d_in[5];
    const float* W_hh_enc = (const float*)d_in[6];
    const float* b_ih_enc = (const float*)d_in[7];
    const float* b_hh_enc = (const float*)d_in[8];
    const float* W_ih_dec = (const float*)d_in[9];
    const float* W_hh_dec = (const float*)d_in[10];
    const float* b_ih_dec = (const float*)d_in[11];
    const float* b_hh_dec = (const float*)d_in[12];
    const float* W_out = (const float*)d_in[13];
    const float* b_out = (const float*)d_in[14];
    float* out = (float*)d_out;

    char* w = (char*)d_ws;
    auto alloc = [&](size_t bytes) {
        char* p = w;
        w += (bytes + 255) & ~(size_t)255;
        return p;
    };
    bf16* embP = (bf16*)alloc((size_t)Tt * Bb * Ee * 2);
    bf16* embF = (bf16*)alloc((size_t)Tt * Bb * Ee * 2);
    bf16* ys = (bf16*)alloc((size_t)Tt * Bb * Hh * 2);
    bf16* hA = (bf16*)alloc((size_t)Bb * Hh * 2);
    bf16* hB = (bf16*)alloc((size_t)Bb * Hh * 2);
    bf16* WembT = (bf16*)alloc((size_t)Ee * Dd * 2);
    bf16* WihEncT = (bf16*)alloc((size_t)H3 * Ee * 2);
    bf16* WhhEncT = (bf16*)alloc((size_t)H3 * Hh * 2);
    bf16* WihDecT = (bf16*)alloc((size_t)H3 * Ee * 2);
    bf16* WhhDecT = (bf16*)alloc((size_t)H3 * Hh * 2);
    bf16* WoutT = (bf16*)alloc((size_t)Dd * Hh * 2);
    unsigned* ctrs = (unsigned*)alloc(16 * 64 * sizeof(unsigned));

    // weight prep (all six transposes fused)
    k_prep<<<9600, 256, 0, stream>>>(W_emb, W_ih_enc, W_hh_enc, W_ih_dec, W_hh_dec, W_out,
                                     WembT, WihEncT, WhhEncT, WihDecT, WhhDecT, WoutT);

    // embeddings (past + future fused)
    k_embed<<<dim3(Tt * Bb / 128, Ee / 64, 2), 256, 0, stream>>>(past, fut, WembT, b_emb, embP, embF);

    // reset group barrier counters
    hipMemsetAsync(ctrs, 0, 16 * 64 * sizeof(unsigned), stream);

    // cooperative persistent recurrent kernel
    void* args[] = {(void*)&embP, (void*)&embF, (void*)&noise,
                    (void*)&WihEncT, (void*)&WhhEncT, (void*)&b_ih_enc, (void*)&b_hh_enc,
                    (void*)&WihDecT, (void*)&WhhDecT, (void*)&b_ih_dec, (void*)&b_hh_dec,
                    (void*)&hA, (void*)&hB, (void*)&ys, (void*)&ctrs};
    hipLaunchCooperativeKernel((const void*)k_gru_all, dim3(256), dim3(256), args, 0, stream);

    // output projection
    k_out<<<dim3(Tt * Bb / 256, Dd / 64), 256, 0, stream>>>(ys, WoutT, b_out, out);
}

// Round 4
// 1096.137 us; speedup vs baseline: 2.7415x; 1.1187x over previous
//
#include <hip/hip_runtime.h>

typedef __bf16 bf16;
typedef __bf16 bf16x8 __attribute__((ext_vector_type(8)));
typedef float f32x4 __attribute__((ext_vector_type(4)));

#define Tt 64
#define Bb 1024
#define Dd 128
#define Ee 256
#define Hh 512
#define H3 1536

__device__ __forceinline__ float sigmf(float x) { return 1.0f / (1.0f + __expf(-x)); }
__device__ __forceinline__ float tanhfast(float x) {
    float e = __expf(2.0f * x);
    return 1.0f - 2.0f / (e + 1.0f);
}

// Cache-bypassing (device-coherent) 16B load / stores: sc0 sc1 reach the coherence
// point (L3) without wbl2/inv of whole caches.
#define LD_SC(dst, bp, OFF) \
    asm volatile("global_load_dwordx4 %0, %1, off offset:" #OFF " sc0 sc1" : "=v"(dst) : "v"(bp))
#define ST_SC(bp, OFF, val) \
    asm volatile("global_store_short %0, %1, off offset:" #OFF " sc0 sc1" :: "v"(bp), "v"(val))
#define LDROW16(arr, bp) \
    LD_SC(arr[0], bp, 0);    LD_SC(arr[1], bp, 64);   LD_SC(arr[2], bp, 128);  LD_SC(arr[3], bp, 192);  \
    LD_SC(arr[4], bp, 256);  LD_SC(arr[5], bp, 320);  LD_SC(arr[6], bp, 384);  LD_SC(arr[7], bp, 448);  \
    LD_SC(arr[8], bp, 512);  LD_SC(arr[9], bp, 576);  LD_SC(arr[10], bp, 640); LD_SC(arr[11], bp, 704); \
    LD_SC(arr[12], bp, 768); LD_SC(arr[13], bp, 832); LD_SC(arr[14], bp, 896); LD_SC(arr[15], bp, 960);

// ---------------- fused weight prep: f32 [K][N] -> bf16 [N][K] for all 6 weights ----------------
__global__ void k_prep(const float* __restrict__ We, const float* __restrict__ Wie, const float* __restrict__ Whe,
                       const float* __restrict__ Wid, const float* __restrict__ Whd, const float* __restrict__ Wo,
                       bf16* __restrict__ dWe, bf16* __restrict__ dWie, bf16* __restrict__ dWhe,
                       bf16* __restrict__ dWid, bf16* __restrict__ dWhd, bf16* __restrict__ dWo) {
    long i = (long)blockIdx.x * 256 + threadIdx.x;
    const float* s;
    bf16* d;
    int K, N;
    if (i < 32768) { s = We; d = dWe; K = Dd; N = Ee; }
    else if ((i -= 32768) < 393216) { s = Wie; d = dWie; K = Ee; N = H3; }
    else if ((i -= 393216) < 786432) { s = Whe; d = dWhe; K = Hh; N = H3; }
    else if ((i -= 786432) < 393216) { s = Wid; d = dWid; K = Ee; N = H3; }
    else if ((i -= 393216) < 786432) { s = Whd; d = dWhd; K = Hh; N = H3; }
    else if ((i -= 786432) < 65536) { s = Wo; d = dWo; K = Hh; N = Dd; }
    else return;
    int n = (int)(i / K), k = (int)(i - (long)n * K);
    d[i] = (bf16)s[(size_t)k * N + n];
}

// ---------------- embed: relu(x @ W_emb + b); past (z=0) and future (z=1) fused ----------------
__global__ __launch_bounds__(256) void k_embed(const float* __restrict__ xP, const float* __restrict__ xF,
                                               const bf16* __restrict__ WT, const float* __restrict__ bias,
                                               bf16* __restrict__ oP, bf16* __restrict__ oF) {
    const int lane = threadIdx.x & 63, wv = threadIdx.x >> 6;
    const float* x = blockIdx.z ? xF : xP;
    bf16* o = blockIdx.z ? oF : oP;
    const int m0w = blockIdx.x * 128 + wv * 32;
    const int c0 = blockIdx.y * 64;
    const int koff = (lane >> 4) * 8;
    f32x4 acc[2][4];
#pragma unroll
    for (int m = 0; m < 2; ++m)
#pragma unroll
        for (int s = 0; s < 4; ++s) acc[m][s] = f32x4{0.f, 0.f, 0.f, 0.f};

    const float* xp0 = x + (size_t)(m0w + (lane & 15)) * Dd + koff;
#pragma unroll
    for (int kc = 0; kc < 4; ++kc) {
        bf16x8 a0, a1;
        {
            float4 f0 = *(const float4*)(xp0 + kc * 32);
            float4 f1 = *(const float4*)(xp0 + kc * 32 + 4);
            a0[0] = (bf16)f0.x; a0[1] = (bf16)f0.y; a0[2] = (bf16)f0.z; a0[3] = (bf16)f0.w;
            a0[4] = (bf16)f1.x; a0[5] = (bf16)f1.y; a0[6] = (bf16)f1.z; a0[7] = (bf16)f1.w;
            float4 g0 = *(const float4*)(xp0 + 16 * Dd + kc * 32);
            float4 g1 = *(const float4*)(xp0 + 16 * Dd + kc * 32 + 4);
            a1[0] = (bf16)g0.x; a1[1] = (bf16)g0.y; a1[2] = (bf16)g0.z; a1[3] = (bf16)g0.w;
            a1[4] = (bf16)g1.x; a1[5] = (bf16)g1.y; a1[6] = (bf16)g1.z; a1[7] = (bf16)g1.w;
        }
#pragma unroll
        for (int s = 0; s < 4; ++s) {
            bf16x8 b = *(const bf16x8*)(WT + (size_t)(c0 + s * 16 + (lane & 15)) * Dd + kc * 32 + koff);
            acc[0][s] = __builtin_amdgcn_mfma_f32_16x16x32_bf16(a0, b, acc[0][s], 0, 0, 0);
            acc[1][s] = __builtin_amdgcn_mfma_f32_16x16x32_bf16(a1, b, acc[1][s], 0, 0, 0);
        }
    }
#pragma unroll
    for (int m = 0; m < 2; ++m)
#pragma unroll
        for (int s = 0; s < 4; ++s) {
            int col = c0 + s * 16 + (lane & 15);
            float bv = bias[col];
#pragma unroll
            for (int r = 0; r < 4; ++r) {
                int row = m0w + m * 16 + (lane >> 4) * 4 + r;
                o[(size_t)row * Ee + col] = (bf16)fmaxf(acc[m][s][r] + bv, 0.0f);
            }
        }
}

// ---------------- persistent cooperative GRU (encoder + noise + decoder) ----------------
// grid 256 = 16 batch-groups (im) x 16 col-blocks (in). Block slice: rows [im*64,+64), h-cols [in*32,+32).
// 8 waves/block: wv -> (rh = wv>>1: 16-row slice, ch = wv&1: 16-col half). B-frags from LDS,
// h A-frags via sc0/sc1 global loads. Sync: per-block monotonic sequence flags (64B apart),
// wave-parallel poll (lane k watches peer k&15) - no atomics, no fences.
__global__ __launch_bounds__(512, 1) void k_gru_all(
    const bf16* __restrict__ embP, const bf16* __restrict__ embF, const float* __restrict__ noise,
    const bf16* __restrict__ WihE, const bf16* __restrict__ WhhE,
    const float* __restrict__ bIhE, const float* __restrict__ bHhE,
    const bf16* __restrict__ WihD, const bf16* __restrict__ WhhD,
    const float* __restrict__ bIhD, const float* __restrict__ bHhD,
    bf16* __restrict__ hA, bf16* __restrict__ hB, bf16* __restrict__ ys, unsigned* __restrict__ flags) {
    __shared__ bf16 Wih[6 * 8 * 64 * 8];    // 49152 B
    __shared__ bf16 Whh[6 * 16 * 64 * 8];   // 98304 B
    const int tid = threadIdx.x;
    const int lane = tid & 63, wv = tid >> 6;
    const int im = blockIdx.x >> 4;  // batch group 0..15
    const int in = blockIdx.x & 15;  // column block 0..15
    const int rh = wv >> 1, ch = wv & 1;
    const int rowb = im * 64 + rh * 16;       // wave's 16 rows start
    const int arow0 = rowb + (lane & 15);     // A row for this lane
    const int koff = (lane >> 4) * 8;
    const int colc = in * 32 + ch * 16 + (lane & 15);  // this lane's output column

    const bf16x8* WihV = (const bf16x8*)Wih;
    const bf16x8* WhhV = (const bf16x8*)Whh;

    auto stage = [&](const bf16* WT, int Kdim, int KC, bf16* lds) {
        int total = 6 * KC * 64;
        for (int idx = tid; idx < total; idx += 512) {
            int ln = idx & 63;
            int kc = (idx >> 6) % KC;
            int s = (idx >> 6) / KC;
            int gate = s >> 1, f = s & 1;
            int col = gate * Hh + in * 32 + f * 16 + (ln & 15);
            int k = kc * 32 + (ln >> 4) * 8;
            *(bf16x8*)(lds + (size_t)idx * 8) = *(const bf16x8*)(WT + (size_t)col * Kdim + k);
        }
    };

    float bi[3], bh[3];
    auto load_bias = [&](const float* bIh, const float* bHh) {
#pragma unroll
        for (int g = 0; g < 3; ++g) {
            bi[g] = bIh[g * Hh + colc];
            bh[g] = bHh[g * Hh + colc];
        }
    };

    // release: wave's sc-stores acked -> block barrier -> one flag store (seq) by tid 0
    auto signal = [&](unsigned seq) {
        asm volatile("s_waitcnt vmcnt(0)" ::: "memory");
        __syncthreads();
        if (tid == 0) {
            unsigned* fp = flags + ((size_t)im * 16 + in) * 16;
            asm volatile("global_store_dword %0, %1, off sc0 sc1" :: "v"(fp), "v"(seq) : "memory");
        }
    };
    // acquire: lane k polls peer (k&15)'s flag; exit when all 16 peers reached seq
    auto wait_flags = [&](unsigned seq) {
        const unsigned* fp = flags + ((size_t)im * 16 + (lane & 15)) * 16;
        for (;;) {
            unsigned v;
            asm volatile("global_load_dword %0, %1, off sc0 sc1\n\ts_waitcnt vmcnt(0)"
                         : "=v"(v) : "v"(fp) : "memory");
            if (__all((int)(v >= seq))) break;
            __builtin_amdgcn_s_sleep(1);
        }
    };

    f32x4 aR, aZ, aNX, aNH;
    auto zacc = [&]() {
        aR = f32x4{0.f, 0.f, 0.f, 0.f};
        aZ = f32x4{0.f, 0.f, 0.f, 0.f};
        aNX = f32x4{0.f, 0.f, 0.f, 0.f};
        aNH = f32x4{0.f, 0.f, 0.f, 0.f};
    };

    auto xp_phase = [&](const bf16* xp) {
        const bf16* ap = xp + (size_t)arow0 * Ee + koff;
#pragma unroll
        for (int kc = 0; kc < 8; ++kc) {
            bf16x8 a = *(const bf16x8*)(ap + kc * 32);
            aR = __builtin_amdgcn_mfma_f32_16x16x32_bf16(a, WihV[((0 + ch) * 8 + kc) * 64 + lane], aR, 0, 0, 0);
            aZ = __builtin_amdgcn_mfma_f32_16x16x32_bf16(a, WihV[((2 + ch) * 8 + kc) * 64 + lane], aZ, 0, 0, 0);
            aNX = __builtin_amdgcn_mfma_f32_16x16x32_bf16(a, WihV[((4 + ch) * 8 + kc) * 64 + lane], aNX, 0, 0, 0);
        }
    };

    auto hw_phase = [&](const bf16* hp) {
        const bf16* h0p = hp + (size_t)arow0 * Hh + koff;
        bf16x8 h0[16];
        LDROW16(h0, h0p);
        asm volatile("s_waitcnt vmcnt(0)" ::: "memory");
        __builtin_amdgcn_sched_barrier(0);
#pragma unroll
        for (int kc = 0; kc < 16; ++kc) {
            aR = __builtin_amdgcn_mfma_f32_16x16x32_bf16(h0[kc], WhhV[((0 + ch) * 16 + kc) * 64 + lane], aR, 0, 0, 0);
            aZ = __builtin_amdgcn_mfma_f32_16x16x32_bf16(h0[kc], WhhV[((2 + ch) * 16 + kc) * 64 + lane], aZ, 0, 0, 0);
            aNH = __builtin_amdgcn_mfma_f32_16x16x32_bf16(h0[kc], WhhV[((4 + ch) * 16 + kc) * 64 + lane], aNH, 0, 0, 0);
        }
    };

    float hreg[4];
#pragma unroll
    for (int i = 0; i < 4; ++i) hreg[i] = 0.0f;

    auto epi = [&](bf16* op) {
        bf16* stb = op + (size_t)(rowb + (lane >> 4) * 4) * Hh + colc;
        unsigned short us[4];
#pragma unroll
        for (int r = 0; r < 4; ++r) {
            float rg = sigmf(aR[r] + bi[0] + bh[0]);
            float zg = sigmf(aZ[r] + bi[1] + bh[1]);
            float ng = tanhfast(aNX[r] + bi[2] + rg * (aNH[r] + bh[2]));
            float hv = (1.0f - zg) * ng + zg * hreg[r];
            hreg[r] = hv;
            us[r] = __builtin_bit_cast(unsigned short, (bf16)hv);
        }
        ST_SC(stb, 0, us[0]);
        ST_SC(stb, 1024, us[1]);
        ST_SC(stb, 2048, us[2]);
        ST_SC(stb, 3072, us[3]);
    };

    // ---------- encoder ----------
    stage(WihE, Ee, 8, Wih);
    stage(WhhE, Hh, 16, Whh);
    load_bias(bIhE, bHhE);
    __syncthreads();

#pragma unroll 1
    for (int t = 0; t < Tt; ++t) {
        zacc();
        xp_phase(embP + (size_t)t * Bb * Ee);
        if (t > 0) {
            wait_flags((unsigned)t);
            hw_phase(((t - 1) & 1) ? hB : hA);
        }
        epi((t & 1) ? hB : hA);
        signal((unsigned)(t + 1));  // seq 1..64
    }

    // ---------- hidden = h_enc + noise; switch to decoder weights ----------
    wait_flags((unsigned)Tt);  // all peers finished READING hA (step Tt-1's hw) and hB
    {
        bf16* stb = hA + (size_t)(rowb + (lane >> 4) * 4) * Hh + colc;
        unsigned short us[4];
#pragma unroll
        for (int r = 0; r < 4; ++r) {
            int row = rowb + (lane >> 4) * 4 + r;
            float v = hreg[r] + noise[(size_t)row * Hh + colc];
            hreg[r] = v;
            us[r] = __builtin_bit_cast(unsigned short, (bf16)v);
        }
        ST_SC(stb, 0, us[0]);
        ST_SC(stb, 1024, us[1]);
        ST_SC(stb, 2048, us[2]);
        ST_SC(stb, 3072, us[3]);
    }
    stage(WihD, Ee, 8, Wih);
    stage(WhhD, Hh, 16, Whh);
    load_bias(bIhD, bHhD);
    signal((unsigned)(Tt + 1));  // seq 65: hA(noise) visible + decoder LDS staged
    wait_flags((unsigned)(Tt + 1));

    // ---------- decoder; ys[t] doubles as the bf16 hidden chain ----------
#pragma unroll 1
    for (int t = 0; t < Tt; ++t) {
        zacc();
        if (t > 0) {
            xp_phase(embF + (size_t)(t - 1) * Bb * Ee);
            wait_flags((unsigned)(Tt + 1 + t));  // peers' ys[t-1] ready (seq 65+t)
        }
        hw_phase(t ? ys + (size_t)(t - 1) * Bb * Hh : hA);
        epi(ys + (size_t)t * Bb * Hh);
        if (t < Tt - 1) signal((unsigned)(Tt + 2 + t));  // seq 66..128
    }
}

// ---------------- out = ys @ W_out + b_out; 64 rows/wave ----------------
__global__ __launch_bounds__(256) void k_out(const bf16* __restrict__ ys, const bf16* __restrict__ WT,
                                             const float* __restrict__ bias, float* __restrict__ out) {
    const int lane = threadIdx.x & 63, wv = threadIdx.x >> 6;
    const int m0w = blockIdx.x * 256 + wv * 64;
    const int c0 = blockIdx.y * 64;
    const int koff = (lane >> 4) * 8;
    f32x4 acc[4][4];
#pragma unroll
    for (int m = 0; m < 4; ++m)
#pragma unroll
        for (int s = 0; s < 4; ++s) acc[m][s] = f32x4{0.f, 0.f, 0.f, 0.f};

    const bf16* ap = ys + (size_t)(m0w + (lane & 15)) * Hh + koff;
#pragma unroll
    for (int kc = 0; kc < 16; ++kc) {
        bf16x8 a0 = *(const bf16x8*)(ap + kc * 32);
        bf16x8 a1 = *(const bf16x8*)(ap + 16 * Hh + kc * 32);
        bf16x8 a2 = *(const bf16x8*)(ap + 32 * Hh + kc * 32);
        bf16x8 a3 = *(const bf16x8*)(ap + 48 * Hh + kc * 32);
#pragma unroll
        for (int s = 0; s < 4; ++s) {
            bf16x8 b = *(const bf16x8*)(WT + (size_t)(c0 + s * 16 + (lane & 15)) * Hh + kc * 32 + koff);
            acc[0][s] = __builtin_amdgcn_mfma_f32_16x16x32_bf16(a0, b, acc[0][s], 0, 0, 0);
            acc[1][s] = __builtin_amdgcn_mfma_f32_16x16x32_bf16(a1, b, acc[1][s], 0, 0, 0);
            acc[2][s] = __builtin_amdgcn_mfma_f32_16x16x32_bf16(a2, b, acc[2][s], 0, 0, 0);
            acc[3][s] = __builtin_amdgcn_mfma_f32_16x16x32_bf16(a3, b, acc[3][s], 0, 0, 0);
        }
    }
#pragma unroll
    for (int m = 0; m < 4; ++m)
#pragma unroll
        for (int s = 0; s < 4; ++s) {
            int col = c0 + s * 16 + (lane & 15);
            float bv = bias[col];
#pragma unroll
            for (int r = 0; r < 4; ++r) {
                int row = m0w + m * 16 + (lane >> 4) * 4 + r;
                out[(size_t)row * Dd + col] = acc[m][s][r] + bv;
            }
        }
}

extern "C" void kernel_launch(void* const* d_in, const int* in_sizes, int n_in,
                              void* d_out, int out_size, void* d_ws, size_t ws_size,
                              hipStream_t stream) {
    const float* past = (const float*)d_in[0];
    const float* fut = (const float*)d_in[1];
    const float* noise = (const float*)d_in[2];
    const float* W_emb = (const float*)d_in[3];
    const float* b_emb = (const float*)d_in[4];
    const float* W_ih_enc = (const float*)d_in[5];
    const float* W_hh_enc = (const float*)d_in[6];
    const float* b_ih_enc = (const float*)d_in[7];
    const float* b_hh_enc = (const float*)d_in[8];
    const float* W_ih_dec = (const float*)d_in[9];
    const float* W_hh_dec = (const float*)d_in[10];
    const float* b_ih_dec = (const float*)d_in[11];
    const float* b_hh_dec = (const float*)d_in[12];
    const float* W_out = (const float*)d_in[13];
    const float* b_out = (const float*)d_in[14];
    float* out = (float*)d_out;

    char* w = (char*)d_ws;
    auto alloc = [&](size_t bytes) {
        char* p = w;
        w += (bytes + 255) & ~(size_t)255;
        return p;
    };
    bf16* embP = (bf16*)alloc((size_t)Tt * Bb * Ee * 2);
    bf16* embF = (bf16*)alloc((size_t)Tt * Bb * Ee * 2);
    bf16* ys = (bf16*)alloc((size_t)Tt * Bb * Hh * 2);
    bf16* hA = (bf16*)alloc((size_t)Bb * Hh * 2);
    bf16* hB = (bf16*)alloc((size_t)Bb * Hh * 2);
    bf16* WembT = (bf16*)alloc((size_t)Ee * Dd * 2);
    bf16* WihEncT = (bf16*)alloc((size_t)H3 * Ee * 2);
    bf16* WhhEncT = (bf16*)alloc((size_t)H3 * Hh * 2);
    bf16* WihDecT = (bf16*)alloc((size_t)H3 * Ee * 2);
    bf16* WhhDecT = (bf16*)alloc((size_t)H3 * Hh * 2);
    bf16* WoutT = (bf16*)alloc((size_t)Dd * Hh * 2);
    unsigned* flags = (unsigned*)alloc(16 * 16 * 64);  // [group][peer], 64B stride

    // weight prep (all six transposes fused)
    k_prep<<<9600, 256, 0, stream>>>(W_emb, W_ih_enc, W_hh_enc, W_ih_dec, W_hh_dec, W_out,
                                     WembT, WihEncT, WhhEncT, WihDecT, WhhDecT, WoutT);

    // embeddings (past + future fused)
    k_embed<<<dim3(Tt * Bb / 128, Ee / 64, 2), 256, 0, stream>>>(past, fut, WembT, b_emb, embP, embF);

    // reset sequence flags
    hipMemsetAsync(flags, 0, 16 * 16 * 64, stream);

    // cooperative persistent recurrent kernel
    void* args[] = {(void*)&embP, (void*)&embF, (void*)&noise,
                    (void*)&WihEncT, (void*)&WhhEncT, (void*)&b_ih_enc, (void*)&b_hh_enc,
                    (void*)&WihDecT, (void*)&WhhDecT, (void*)&b_ih_dec, (void*)&b_hh_dec,
                    (void*)&hA, (void*)&hB, (void*)&ys, (void*)&flags};
    hipLaunchCooperativeKernel((const void*)k_gru_all, dim3(256), dim3(512), args, 0, stream);

    // output projection
    k_out<<<dim3(Tt * Bb / 256, Dd / 64), 256, 0, stream>>>(ys, WoutT, b_out, out);
}

// Round 5
// 1069.209 us; speedup vs baseline: 2.8105x; 1.0252x over previous
//
#include <hip/hip_runtime.h>

typedef __bf16 bf16;
typedef __bf16 bf16x8 __attribute__((ext_vector_type(8)));
typedef float f32x4 __attribute__((ext_vector_type(4)));

#define Tt 64
#define Bb 1024
#define Dd 128
#define Ee 256
#define Hh 512
#define H3 1536

__device__ __forceinline__ float sigmf(float x) { return 1.0f / (1.0f + __expf(-x)); }
__device__ __forceinline__ float tanhfast(float x) {
    float e = __expf(2.0f * x);
    return 1.0f - 2.0f / (e + 1.0f);
}

// Device-coherent (L3-level) ops; sc0 sc1 = system/device scope, no cache nukes.
#define LD_SC(dst, bp, OFF) \
    asm volatile("global_load_dwordx4 %0, %1, off offset:" #OFF " sc0 sc1" : "=v"(dst) : "v"(bp))
#define ST_SC(bp, OFF, val) \
    asm volatile("global_store_short %0, %1, off offset:" #OFF " sc0 sc1" :: "v"(bp), "v"(val))

// ---------------- fused weight prep: f32 [K][N] -> bf16 [N][K] for all 6 weights ----------------
__global__ void k_prep(const float* __restrict__ We, const float* __restrict__ Wie, const float* __restrict__ Whe,
                       const float* __restrict__ Wid, const float* __restrict__ Whd, const float* __restrict__ Wo,
                       bf16* __restrict__ dWe, bf16* __restrict__ dWie, bf16* __restrict__ dWhe,
                       bf16* __restrict__ dWid, bf16* __restrict__ dWhd, bf16* __restrict__ dWo) {
    long i = (long)blockIdx.x * 256 + threadIdx.x;
    const float* s;
    bf16* d;
    int K, N;
    if (i < 32768) { s = We; d = dWe; K = Dd; N = Ee; }
    else if ((i -= 32768) < 393216) { s = Wie; d = dWie; K = Ee; N = H3; }
    else if ((i -= 393216) < 786432) { s = Whe; d = dWhe; K = Hh; N = H3; }
    else if ((i -= 786432) < 393216) { s = Wid; d = dWid; K = Ee; N = H3; }
    else if ((i -= 393216) < 786432) { s = Whd; d = dWhd; K = Hh; N = H3; }
    else if ((i -= 786432) < 65536) { s = Wo; d = dWo; K = Hh; N = Dd; }
    else return;
    int n = (int)(i / K), k = (int)(i - (long)n * K);
    d[i] = (bf16)s[(size_t)k * N + n];
}

// ---------------- embed: relu(x @ W_emb + b); past (z=0) and future (z=1) fused ----------------
__global__ __launch_bounds__(256) void k_embed(const float* __restrict__ xP, const float* __restrict__ xF,
                                               const bf16* __restrict__ WT, const float* __restrict__ bias,
                                               bf16* __restrict__ oP, bf16* __restrict__ oF) {
    const int lane = threadIdx.x & 63, wv = threadIdx.x >> 6;
    const float* x = blockIdx.z ? xF : xP;
    bf16* o = blockIdx.z ? oF : oP;
    const int m0w = blockIdx.x * 128 + wv * 32;
    const int c0 = blockIdx.y * 64;
    const int koff = (lane >> 4) * 8;
    f32x4 acc[2][4];
#pragma unroll
    for (int m = 0; m < 2; ++m)
#pragma unroll
        for (int s = 0; s < 4; ++s) acc[m][s] = f32x4{0.f, 0.f, 0.f, 0.f};

    const float* xp0 = x + (size_t)(m0w + (lane & 15)) * Dd + koff;
#pragma unroll
    for (int kc = 0; kc < 4; ++kc) {
        bf16x8 a0, a1;
        {
            float4 f0 = *(const float4*)(xp0 + kc * 32);
            float4 f1 = *(const float4*)(xp0 + kc * 32 + 4);
            a0[0] = (bf16)f0.x; a0[1] = (bf16)f0.y; a0[2] = (bf16)f0.z; a0[3] = (bf16)f0.w;
            a0[4] = (bf16)f1.x; a0[5] = (bf16)f1.y; a0[6] = (bf16)f1.z; a0[7] = (bf16)f1.w;
            float4 g0 = *(const float4*)(xp0 + 16 * Dd + kc * 32);
            float4 g1 = *(const float4*)(xp0 + 16 * Dd + kc * 32 + 4);
            a1[0] = (bf16)g0.x; a1[1] = (bf16)g0.y; a1[2] = (bf16)g0.z; a1[3] = (bf16)g0.w;
            a1[4] = (bf16)g1.x; a1[5] = (bf16)g1.y; a1[6] = (bf16)g1.z; a1[7] = (bf16)g1.w;
        }
#pragma unroll
        for (int s = 0; s < 4; ++s) {
            bf16x8 b = *(const bf16x8*)(WT + (size_t)(c0 + s * 16 + (lane & 15)) * Dd + kc * 32 + koff);
            acc[0][s] = __builtin_amdgcn_mfma_f32_16x16x32_bf16(a0, b, acc[0][s], 0, 0, 0);
            acc[1][s] = __builtin_amdgcn_mfma_f32_16x16x32_bf16(a1, b, acc[1][s], 0, 0, 0);
        }
    }
#pragma unroll
    for (int m = 0; m < 2; ++m)
#pragma unroll
        for (int s = 0; s < 4; ++s) {
            int col = c0 + s * 16 + (lane & 15);
            float bv = bias[col];
#pragma unroll
            for (int r = 0; r < 4; ++r) {
                int row = m0w + m * 16 + (lane >> 4) * 4 + r;
                o[(size_t)row * Ee + col] = (bf16)fmaxf(acc[m][s][r] + bv, 0.0f);
            }
        }
}

// ---------------- persistent cooperative GRU: wave-free-running version ----------------
// 256 blocks = 16 groups (im) x 16 col-blocks (in), XCD-affine remap (perf-only).
// 8 waves/block: rh = wv>>1 (16-row slice), ch = wv&1 (16-col half).
// Sync domain = (im, rh): 32 waves (16 blocks x 2 ch). Per-wave flags, packed 32x4B
// per domain (2 cache lines). No per-step __syncthreads. hW consumes peer p's cols
// as K-chunk kc=p: wait peer p's 2 flags -> issue h-load p (pipelined).
__global__ __launch_bounds__(512, 1) void k_gru_all(
    const bf16* __restrict__ embP, const bf16* __restrict__ embF, const float* __restrict__ noise,
    const bf16* __restrict__ WihE, const bf16* __restrict__ WhhE,
    const float* __restrict__ bIhE, const float* __restrict__ bHhE,
    const bf16* __restrict__ WihD, const bf16* __restrict__ WhhD,
    const float* __restrict__ bIhD, const float* __restrict__ bHhD,
    bf16* __restrict__ hA, bf16* __restrict__ hB, bf16* __restrict__ ys, unsigned* __restrict__ flags) {
    __shared__ bf16 Wih[6 * 8 * 64 * 8];    // 49152 B
    __shared__ bf16 Whh[6 * 16 * 64 * 8];   // 98304 B
    const int tid = threadIdx.x;
    const int lane = tid & 63, wv = tid >> 6;
    // XCD-affine remap: under round-robin placement (xcd = bid & 7), each group (im)
    // lands entirely on one XCD -> emb re-reads hit that XCD's L2. Correct regardless.
    const int bid = blockIdx.x;
    const int im = (bid & 7) * 2 + (bid >> 7);
    const int in = (bid >> 3) & 15;
    const int rh = wv >> 1, ch = wv & 1;
    const int rowb = im * 64 + rh * 16;
    const int arow0 = rowb + (lane & 15);
    const int koff = (lane >> 4) * 8;
    const int colc = in * 32 + ch * 16 + (lane & 15);
    unsigned* dom = flags + ((size_t)im * 4 + rh) * 32;  // 32 flags x 4B = 128B
    const int myidx = in * 2 + ch;

    const bf16x8* WihV = (const bf16x8*)Wih;
    const bf16x8* WhhV = (const bf16x8*)Whh;

    auto stage = [&](const bf16* WT, int Kdim, int KC, bf16* lds) {
        int total = 6 * KC * 64;
        for (int idx = tid; idx < total; idx += 512) {
            int ln = idx & 63;
            int kc = (idx >> 6) % KC;
            int s = (idx >> 6) / KC;
            int gate = s >> 1, f = s & 1;
            int col = gate * Hh + in * 32 + f * 16 + (ln & 15);
            int k = kc * 32 + (ln >> 4) * 8;
            *(bf16x8*)(lds + (size_t)idx * 8) = *(const bf16x8*)(WT + (size_t)col * Kdim + k);
        }
    };

    float bi[3], bh[3];
    auto load_bias = [&](const float* bIh, const float* bHh) {
#pragma unroll
        for (int g = 0; g < 3; ++g) {
            bi[g] = bIh[g * Hh + colc];
            bh[g] = bHh[g * Hh + colc];
        }
    };

    // per-WAVE release: my stores acked -> lane0 publishes seq. No block barrier.
    auto signal = [&](unsigned seq) {
        asm volatile("s_waitcnt vmcnt(0)" ::: "memory");
        if (lane == 0) {
            unsigned* fp = dom + myidx;
            asm volatile("global_store_dword %0, %1, off sc0 sc1" :: "v"(fp), "v"(seq) : "memory");
        }
    };
    // one poll = one dword load (lane k -> flag k&31; 2 cache lines) -> ballot
    auto poll = [&](unsigned seq) -> unsigned long long {
        unsigned v;
        const unsigned* fp = dom + (lane & 31);
        asm volatile("global_load_dword %0, %1, off sc0 sc1\n\ts_waitcnt vmcnt(0)"
                     : "=v"(v) : "v"(fp) : "memory");
        return __ballot((int)(v >= seq));
    };
    auto wait_all = [&](unsigned seq) {
        while (poll(seq) != ~0ULL) __builtin_amdgcn_s_sleep(2);
    };

    f32x4 aR, aZ, aNX, aNH;
    auto zacc = [&]() {
        aR = f32x4{0.f, 0.f, 0.f, 0.f};
        aZ = f32x4{0.f, 0.f, 0.f, 0.f};
        aNX = f32x4{0.f, 0.f, 0.f, 0.f};
        aNH = f32x4{0.f, 0.f, 0.f, 0.f};
    };

    auto xp_phase = [&](const bf16* xp) {
        const bf16* ap = xp + (size_t)arow0 * Ee + koff;
#pragma unroll
        for (int kc = 0; kc < 8; ++kc) {
            bf16x8 a = *(const bf16x8*)(ap + kc * 32);
            aR = __builtin_amdgcn_mfma_f32_16x16x32_bf16(a, WihV[((0 + ch) * 8 + kc) * 64 + lane], aR, 0, 0, 0);
            aZ = __builtin_amdgcn_mfma_f32_16x16x32_bf16(a, WihV[((2 + ch) * 8 + kc) * 64 + lane], aZ, 0, 0, 0);
            aNX = __builtin_amdgcn_mfma_f32_16x16x32_bf16(a, WihV[((4 + ch) * 8 + kc) * 64 + lane], aNX, 0, 0, 0);
        }
    };

    // hW with per-peer pipelined waits: chunk kc=p comes from peer block in=p (flags 2p,2p+1).
    auto hw_phase = [&](const bf16* hp, unsigned seq) {
        const bf16* h0p = hp + (size_t)arow0 * Hh + koff;
        bf16x8 h0[16];
        unsigned long long rdy = poll(seq);
#define HSTEP(p, OFF) \
        while (((rdy >> (2 * p)) & 3ULL) != 3ULL) { __builtin_amdgcn_s_sleep(2); rdy = poll(seq); } \
        LD_SC(h0[p], h0p, OFF);
        HSTEP(0, 0)    HSTEP(1, 64)   HSTEP(2, 128)  HSTEP(3, 192)
        HSTEP(4, 256)  HSTEP(5, 320)  HSTEP(6, 384)  HSTEP(7, 448)
        HSTEP(8, 512)  HSTEP(9, 576)  HSTEP(10, 640) HSTEP(11, 704)
        HSTEP(12, 768) HSTEP(13, 832) HSTEP(14, 896) HSTEP(15, 960)
#undef HSTEP
        asm volatile("s_waitcnt vmcnt(0)" ::: "memory");
        __builtin_amdgcn_sched_barrier(0);
#pragma unroll
        for (int kc = 0; kc < 16; ++kc) {
            aR = __builtin_amdgcn_mfma_f32_16x16x32_bf16(h0[kc], WhhV[((0 + ch) * 16 + kc) * 64 + lane], aR, 0, 0, 0);
            aZ = __builtin_amdgcn_mfma_f32_16x16x32_bf16(h0[kc], WhhV[((2 + ch) * 16 + kc) * 64 + lane], aZ, 0, 0, 0);
            aNH = __builtin_amdgcn_mfma_f32_16x16x32_bf16(h0[kc], WhhV[((4 + ch) * 16 + kc) * 64 + lane], aNH, 0, 0, 0);
        }
    };

    float hreg[4];
#pragma unroll
    for (int i = 0; i < 4; ++i) hreg[i] = 0.0f;

    auto epi = [&](bf16* op) {
        bf16* stb = op + (size_t)(rowb + (lane >> 4) * 4) * Hh + colc;
        unsigned short us[4];
#pragma unroll
        for (int r = 0; r < 4; ++r) {
            float rg = sigmf(aR[r] + bi[0] + bh[0]);
            float zg = sigmf(aZ[r] + bi[1] + bh[1]);
            float ng = tanhfast(aNX[r] + bi[2] + rg * (aNH[r] + bh[2]));
            float hv = (1.0f - zg) * ng + zg * hreg[r];
            hreg[r] = hv;
            us[r] = __builtin_bit_cast(unsigned short, (bf16)hv);
        }
        ST_SC(stb, 0, us[0]);
        ST_SC(stb, 1024, us[1]);
        ST_SC(stb, 2048, us[2]);
        ST_SC(stb, 3072, us[3]);
    };

    // ---------- encoder ----------
    stage(WihE, Ee, 8, Wih);
    stage(WhhE, Hh, 16, Whh);
    load_bias(bIhE, bHhE);
    __syncthreads();

#pragma unroll 1
    for (int t = 0; t < Tt; ++t) {
        zacc();
        xp_phase(embP + (size_t)t * Bb * Ee);
        if (t > 0) hw_phase(((t - 1) & 1) ? hB : hA, (unsigned)t);
        epi((t & 1) ? hB : hA);
        signal((unsigned)(t + 1));  // seq 1..64
    }

    // ---------- hidden = h_enc + noise; switch to decoder weights ----------
    wait_all((unsigned)Tt);  // rh-domain peers done reading hA (enc step 63)
    {
        bf16* stb = hA + (size_t)(rowb + (lane >> 4) * 4) * Hh + colc;
        unsigned short us[4];
#pragma unroll
        for (int r = 0; r < 4; ++r) {
            int row = rowb + (lane >> 4) * 4 + r;
            float v = hreg[r] + noise[(size_t)row * Hh + colc];
            hreg[r] = v;
            us[r] = __builtin_bit_cast(unsigned short, (bf16)v);
        }
        ST_SC(stb, 0, us[0]);
        ST_SC(stb, 1024, us[1]);
        ST_SC(stb, 2048, us[2]);
        ST_SC(stb, 3072, us[3]);
    }
    __syncthreads();  // all waves of this block past their enc LDS reads
    stage(WihD, Ee, 8, Wih);
    stage(WhhD, Hh, 16, Whh);
    __syncthreads();  // decoder LDS staged before any wave's dec reads
    load_bias(bIhD, bHhD);
    signal((unsigned)(Tt + 1));  // seq 65: hA(+noise) visible

    // ---------- decoder; ys[t] doubles as the bf16 hidden chain ----------
#pragma unroll 1
    for (int t = 0; t < Tt; ++t) {
        zacc();
        if (t > 0) xp_phase(embF + (size_t)(t - 1) * Bb * Ee);
        hw_phase(t ? ys + (size_t)(t - 1) * Bb * Hh : hA, (unsigned)(Tt + 1 + t));  // seq 65+t
        epi(ys + (size_t)t * Bb * Hh);
        if (t < Tt - 1) signal((unsigned)(Tt + 2 + t));  // seq 66..128
    }
}

// ---------------- out = ys @ W_out + b_out; 64 rows/wave ----------------
__global__ __launch_bounds__(256) void k_out(const bf16* __restrict__ ys, const bf16* __restrict__ WT,
                                             const float* __restrict__ bias, float* __restrict__ out) {
    const int lane = threadIdx.x & 63, wv = threadIdx.x >> 6;
    const int m0w = blockIdx.x * 256 + wv * 64;
    const int c0 = blockIdx.y * 64;
    const int koff = (lane >> 4) * 8;
    f32x4 acc[4][4];
#pragma unroll
    for (int m = 0; m < 4; ++m)
#pragma unroll
        for (int s = 0; s < 4; ++s) acc[m][s] = f32x4{0.f, 0.f, 0.f, 0.f};

    const bf16* ap = ys + (size_t)(m0w + (lane & 15)) * Hh + koff;
#pragma unroll
    for (int kc = 0; kc < 16; ++kc) {
        bf16x8 a0 = *(const bf16x8*)(ap + kc * 32);
        bf16x8 a1 = *(const bf16x8*)(ap + 16 * Hh + kc * 32);
        bf16x8 a2 = *(const bf16x8*)(ap + 32 * Hh + kc * 32);
        bf16x8 a3 = *(const bf16x8*)(ap + 48 * Hh + kc * 32);
#pragma unroll
        for (int s = 0; s < 4; ++s) {
            bf16x8 b = *(const bf16x8*)(WT + (size_t)(c0 + s * 16 + (lane & 15)) * Hh + kc * 32 + koff);
            acc[0][s] = __builtin_amdgcn_mfma_f32_16x16x32_bf16(a0, b, acc[0][s], 0, 0, 0);
            acc[1][s] = __builtin_amdgcn_mfma_f32_16x16x32_bf16(a1, b, acc[1][s], 0, 0, 0);
            acc[2][s] = __builtin_amdgcn_mfma_f32_16x16x32_bf16(a2, b, acc[2][s], 0, 0, 0);
            acc[3][s] = __builtin_amdgcn_mfma_f32_16x16x32_bf16(a3, b, acc[3][s], 0, 0, 0);
        }
    }
#pragma unroll
    for (int m = 0; m < 4; ++m)
#pragma unroll
        for (int s = 0; s < 4; ++s) {
            int col = c0 + s * 16 + (lane & 15);
            float bv = bias[col];
#pragma unroll
            for (int r = 0; r < 4; ++r) {
                int row = m0w + m * 16 + (lane >> 4) * 4 + r;
                out[(size_t)row * Dd + col] = acc[m][s][r] + bv;
            }
        }
}

extern "C" void kernel_launch(void* const* d_in, const int* in_sizes, int n_in,
                              void* d_out, int out_size, void* d_ws, size_t ws_size,
                              hipStream_t stream) {
    const float* past = (const float*)d_in[0];
    const float* fut = (const float*)d_in[1];
    const float* noise = (const float*)d_in[2];
    const float* W_emb = (const float*)d_in[3];
    const float* b_emb = (const float*)d_in[4];
    const float* W_ih_enc = (const float*)d_in[5];
    const float* W_hh_enc = (const float*)d_in[6];
    const float* b_ih_enc = (const float*)d_in[7];
    const float* b_hh_enc = (const float*)d_in[8];
    const float* W_ih_dec = (const float*)d_in[9];
    const float* W_hh_dec = (const float*)d_in[10];
    const float* b_ih_dec = (const float*)d_in[11];
    const float* b_hh_dec = (const float*)d_in[12];
    const float* W_out = (const float*)d_in[13];
    const float* b_out = (const float*)d_in[14];
    float* out = (float*)d_out;

    char* w = (char*)d_ws;
    auto alloc = [&](size_t bytes) {
        char* p = w;
        w += (bytes + 255) & ~(size_t)255;
        return p;
    };
    bf16* embP = (bf16*)alloc((size_t)Tt * Bb * Ee * 2);
    bf16* embF = (bf16*)alloc((size_t)Tt * Bb * Ee * 2);
    bf16* ys = (bf16*)alloc((size_t)Tt * Bb * Hh * 2);
    bf16* hA = (bf16*)alloc((size_t)Bb * Hh * 2);
    bf16* hB = (bf16*)alloc((size_t)Bb * Hh * 2);
    bf16* WembT = (bf16*)alloc((size_t)Ee * Dd * 2);
    bf16* WihEncT = (bf16*)alloc((size_t)H3 * Ee * 2);
    bf16* WhhEncT = (bf16*)alloc((size_t)H3 * Hh * 2);
    bf16* WihDecT = (bf16*)alloc((size_t)H3 * Ee * 2);
    bf16* WhhDecT = (bf16*)alloc((size_t)H3 * Hh * 2);
    bf16* WoutT = (bf16*)alloc((size_t)Dd * Hh * 2);
    unsigned* flags = (unsigned*)alloc(16 * 4 * 32 * sizeof(unsigned));  // [im][rh][32]

    // weight prep (all six transposes fused)
    k_prep<<<9600, 256, 0, stream>>>(W_emb, W_ih_enc, W_hh_enc, W_ih_dec, W_hh_dec, W_out,
                                     WembT, WihEncT, WhhEncT, WihDecT, WhhDecT, WoutT);

    // embeddings (past + future fused)
    k_embed<<<dim3(Tt * Bb / 128, Ee / 64, 2), 256, 0, stream>>>(past, fut, WembT, b_emb, embP, embF);

    // reset sequence flags
    hipMemsetAsync(flags, 0, 16 * 4 * 32 * sizeof(unsigned), stream);

    // cooperative persistent recurrent kernel
    void* args[] = {(void*)&embP, (void*)&embF, (void*)&noise,
                    (void*)&WihEncT, (void*)&WhhEncT, (void*)&b_ih_enc, (void*)&b_hh_enc,
                    (void*)&WihDecT, (void*)&WhhDecT, (void*)&b_ih_dec, (void*)&b_hh_dec,
                    (void*)&hA, (void*)&hB, (void*)&ys, (void*)&flags};
    hipLaunchCooperativeKernel((const void*)k_gru_all, dim3(256), dim3(512), args, 0, stream);

    // output projection
    k_out<<<dim3(Tt * Bb / 256, Dd / 64), 256, 0, stream>>>(ys, WoutT, b_out, out);
}

// Round 6
// 1040.143 us; speedup vs baseline: 2.8890x; 1.0279x over previous
//
#include <hip/hip_runtime.h>

typedef __bf16 bf16;
typedef __bf16 bf16x8 __attribute__((ext_vector_type(8)));
typedef float f32x4 __attribute__((ext_vector_type(4)));

#define Tt 64
#define Bb 1024
#define Dd 128
#define Ee 256
#define Hh 512
#define H3 1536

__device__ __forceinline__ float sigmf(float x) { return 1.0f / (1.0f + __expf(-x)); }
__device__ __forceinline__ float tanhfast(float x) {
    float e = __expf(2.0f * x);
    return 1.0f - 2.0f / (e + 1.0f);
}

// AGENT-scope (device-coherent) ops: sc1 = agent on gfx95x. Coherence point is the
// memory-side L3 (Infinity Cache), NOT HBM. (sc0 sc1 = system scope = HBM round trips —
// that was round 5's hidden cost.)
#define LD_SC(dst, bp, OFF) \
    asm volatile("global_load_dwordx4 %0, %1, off offset:" #OFF " sc1" : "=v"(dst) : "v"(bp))
#define ST_SC(bp, OFF, val) \
    asm volatile("global_store_short %0, %1, off offset:" #OFF " sc1" :: "v"(bp), "v"(val))

// ---------------- fused weight prep: f32 [K][N] -> bf16 [N][K] for all 6 weights ----------------
__global__ void k_prep(const float* __restrict__ We, const float* __restrict__ Wie, const float* __restrict__ Whe,
                       const float* __restrict__ Wid, const float* __restrict__ Whd, const float* __restrict__ Wo,
                       bf16* __restrict__ dWe, bf16* __restrict__ dWie, bf16* __restrict__ dWhe,
                       bf16* __restrict__ dWid, bf16* __restrict__ dWhd, bf16* __restrict__ dWo) {
    long i = (long)blockIdx.x * 256 + threadIdx.x;
    const float* s;
    bf16* d;
    int K, N;
    if (i < 32768) { s = We; d = dWe; K = Dd; N = Ee; }
    else if ((i -= 32768) < 393216) { s = Wie; d = dWie; K = Ee; N = H3; }
    else if ((i -= 393216) < 786432) { s = Whe; d = dWhe; K = Hh; N = H3; }
    else if ((i -= 786432) < 393216) { s = Wid; d = dWid; K = Ee; N = H3; }
    else if ((i -= 393216) < 786432) { s = Whd; d = dWhd; K = Hh; N = H3; }
    else if ((i -= 786432) < 65536) { s = Wo; d = dWo; K = Hh; N = Dd; }
    else return;
    int n = (int)(i / K), k = (int)(i - (long)n * K);
    d[i] = (bf16)s[(size_t)k * N + n];
}

// ---------------- embed: relu(x @ W_emb + b); past (z=0) and future (z=1) fused ----------------
__global__ __launch_bounds__(256) void k_embed(const float* __restrict__ xP, const float* __restrict__ xF,
                                               const bf16* __restrict__ WT, const float* __restrict__ bias,
                                               bf16* __restrict__ oP, bf16* __restrict__ oF) {
    const int lane = threadIdx.x & 63, wv = threadIdx.x >> 6;
    const float* x = blockIdx.z ? xF : xP;
    bf16* o = blockIdx.z ? oF : oP;
    const int m0w = blockIdx.x * 128 + wv * 32;
    const int c0 = blockIdx.y * 64;
    const int koff = (lane >> 4) * 8;
    f32x4 acc[2][4];
#pragma unroll
    for (int m = 0; m < 2; ++m)
#pragma unroll
        for (int s = 0; s < 4; ++s) acc[m][s] = f32x4{0.f, 0.f, 0.f, 0.f};

    const float* xp0 = x + (size_t)(m0w + (lane & 15)) * Dd + koff;
#pragma unroll
    for (int kc = 0; kc < 4; ++kc) {
        bf16x8 a0, a1;
        {
            float4 f0 = *(const float4*)(xp0 + kc * 32);
            float4 f1 = *(const float4*)(xp0 + kc * 32 + 4);
            a0[0] = (bf16)f0.x; a0[1] = (bf16)f0.y; a0[2] = (bf16)f0.z; a0[3] = (bf16)f0.w;
            a0[4] = (bf16)f1.x; a0[5] = (bf16)f1.y; a0[6] = (bf16)f1.z; a0[7] = (bf16)f1.w;
            float4 g0 = *(const float4*)(xp0 + 16 * Dd + kc * 32);
            float4 g1 = *(const float4*)(xp0 + 16 * Dd + kc * 32 + 4);
            a1[0] = (bf16)g0.x; a1[1] = (bf16)g0.y; a1[2] = (bf16)g0.z; a1[3] = (bf16)g0.w;
            a1[4] = (bf16)g1.x; a1[5] = (bf16)g1.y; a1[6] = (bf16)g1.z; a1[7] = (bf16)g1.w;
        }
#pragma unroll
        for (int s = 0; s < 4; ++s) {
            bf16x8 b = *(const bf16x8*)(WT + (size_t)(c0 + s * 16 + (lane & 15)) * Dd + kc * 32 + koff);
            acc[0][s] = __builtin_amdgcn_mfma_f32_16x16x32_bf16(a0, b, acc[0][s], 0, 0, 0);
            acc[1][s] = __builtin_amdgcn_mfma_f32_16x16x32_bf16(a1, b, acc[1][s], 0, 0, 0);
        }
    }
#pragma unroll
    for (int m = 0; m < 2; ++m)
#pragma unroll
        for (int s = 0; s < 4; ++s) {
            int col = c0 + s * 16 + (lane & 15);
            float bv = bias[col];
#pragma unroll
            for (int r = 0; r < 4; ++r) {
                int row = m0w + m * 16 + (lane >> 4) * 4 + r;
                o[(size_t)row * Ee + col] = (bf16)fmaxf(acc[m][s][r] + bv, 0.0f);
            }
        }
}

// ---------------- persistent cooperative GRU: wave-free-running version ----------------
// 256 blocks = 16 groups (im) x 16 col-blocks (in), XCD-affine remap (perf-only).
// 8 waves/block: rh = wv>>1 (16-row slice), ch = wv&1 (16-col half).
// Sync domain = (im, rh): 32 waves (16 blocks x 2 ch). Per-wave flags, packed 32x4B
// per domain (2 cache lines). No per-step __syncthreads. hW consumes peer p's cols
// as K-chunk kc=p: wait peer p's 2 flags -> issue h-load p (pipelined).
__global__ __launch_bounds__(512, 1) void k_gru_all(
    const bf16* __restrict__ embP, const bf16* __restrict__ embF, const float* __restrict__ noise,
    const bf16* __restrict__ WihE, const bf16* __restrict__ WhhE,
    const float* __restrict__ bIhE, const float* __restrict__ bHhE,
    const bf16* __restrict__ WihD, const bf16* __restrict__ WhhD,
    const float* __restrict__ bIhD, const float* __restrict__ bHhD,
    bf16* __restrict__ hA, bf16* __restrict__ hB, bf16* __restrict__ ys, unsigned* __restrict__ flags) {
    __shared__ bf16 Wih[6 * 8 * 64 * 8];    // 49152 B
    __shared__ bf16 Whh[6 * 16 * 64 * 8];   // 98304 B
    const int tid = threadIdx.x;
    const int lane = tid & 63, wv = tid >> 6;
    // XCD-affine remap: under round-robin placement (xcd = bid & 7), each group (im)
    // lands entirely on one XCD -> emb re-reads hit that XCD's L2. Correct regardless.
    const int bid = blockIdx.x;
    const int im = (bid & 7) * 2 + (bid >> 7);
    const int in = (bid >> 3) & 15;
    const int rh = wv >> 1, ch = wv & 1;
    const int rowb = im * 64 + rh * 16;
    const int arow0 = rowb + (lane & 15);
    const int koff = (lane >> 4) * 8;
    const int colc = in * 32 + ch * 16 + (lane & 15);
    unsigned* dom = flags + ((size_t)im * 4 + rh) * 32;  // 32 flags x 4B = 128B
    const int myidx = in * 2 + ch;

    const bf16x8* WihV = (const bf16x8*)Wih;
    const bf16x8* WhhV = (const bf16x8*)Whh;

    auto stage = [&](const bf16* WT, int Kdim, int KC, bf16* lds) {
        int total = 6 * KC * 64;
        for (int idx = tid; idx < total; idx += 512) {
            int ln = idx & 63;
            int kc = (idx >> 6) % KC;
            int s = (idx >> 6) / KC;
            int gate = s >> 1, f = s & 1;
            int col = gate * Hh + in * 32 + f * 16 + (ln & 15);
            int k = kc * 32 + (ln >> 4) * 8;
            *(bf16x8*)(lds + (size_t)idx * 8) = *(const bf16x8*)(WT + (size_t)col * Kdim + k);
        }
    };

    float bi[3], bh[3];
    auto load_bias = [&](const float* bIh, const float* bHh) {
#pragma unroll
        for (int g = 0; g < 3; ++g) {
            bi[g] = bIh[g * Hh + colc];
            bh[g] = bHh[g * Hh + colc];
        }
    };

    // per-WAVE release: my stores acked (at L3) -> lane0 publishes seq. No block barrier.
    auto signal = [&](unsigned seq) {
        asm volatile("s_waitcnt vmcnt(0)" ::: "memory");
        if (lane == 0) {
            unsigned* fp = dom + myidx;
            asm volatile("global_store_dword %0, %1, off sc1" :: "v"(fp), "v"(seq) : "memory");
        }
    };
    // one poll = one dword load (lane k -> flag k&31; 2 cache lines) -> ballot
    auto poll = [&](unsigned seq) -> unsigned long long {
        unsigned v;
        const unsigned* fp = dom + (lane & 31);
        asm volatile("global_load_dword %0, %1, off sc1\n\ts_waitcnt vmcnt(0)"
                     : "=v"(v) : "v"(fp) : "memory");
        return __ballot((int)(v >= seq));
    };
    auto wait_all = [&](unsigned seq) {
        while (poll(seq) != ~0ULL) __builtin_amdgcn_s_sleep(2);
    };

    f32x4 aR, aZ, aNX, aNH;
    auto zacc = [&]() {
        aR = f32x4{0.f, 0.f, 0.f, 0.f};
        aZ = f32x4{0.f, 0.f, 0.f, 0.f};
        aNX = f32x4{0.f, 0.f, 0.f, 0.f};
        aNH = f32x4{0.f, 0.f, 0.f, 0.f};
    };

    auto xp_phase = [&](const bf16* xp) {
        const bf16* ap = xp + (size_t)arow0 * Ee + koff;
#pragma unroll
        for (int kc = 0; kc < 8; ++kc) {
            bf16x8 a = *(const bf16x8*)(ap + kc * 32);
            aR = __builtin_amdgcn_mfma_f32_16x16x32_bf16(a, WihV[((0 + ch) * 8 + kc) * 64 + lane], aR, 0, 0, 0);
            aZ = __builtin_amdgcn_mfma_f32_16x16x32_bf16(a, WihV[((2 + ch) * 8 + kc) * 64 + lane], aZ, 0, 0, 0);
            aNX = __builtin_amdgcn_mfma_f32_16x16x32_bf16(a, WihV[((4 + ch) * 8 + kc) * 64 + lane], aNX, 0, 0, 0);
        }
    };

    // hW with per-peer pipelined waits: chunk kc=p comes from peer block in=p (flags 2p,2p+1).
    auto hw_phase = [&](const bf16* hp, unsigned seq) {
        const bf16* h0p = hp + (size_t)arow0 * Hh + koff;
        bf16x8 h0[16];
        unsigned long long rdy = poll(seq);
#define HSTEP(p, OFF) \
        while (((rdy >> (2 * p)) & 3ULL) != 3ULL) { __builtin_amdgcn_s_sleep(2); rdy = poll(seq); } \
        LD_SC(h0[p], h0p, OFF);
        HSTEP(0, 0)    HSTEP(1, 64)   HSTEP(2, 128)  HSTEP(3, 192)
        HSTEP(4, 256)  HSTEP(5, 320)  HSTEP(6, 384)  HSTEP(7, 448)
        HSTEP(8, 512)  HSTEP(9, 576)  HSTEP(10, 640) HSTEP(11, 704)
        HSTEP(12, 768) HSTEP(13, 832) HSTEP(14, 896) HSTEP(15, 960)
#undef HSTEP
        asm volatile("s_waitcnt vmcnt(0)" ::: "memory");
        __builtin_amdgcn_sched_barrier(0);
#pragma unroll
        for (int kc = 0; kc < 16; ++kc) {
            aR = __builtin_amdgcn_mfma_f32_16x16x32_bf16(h0[kc], WhhV[((0 + ch) * 16 + kc) * 64 + lane], aR, 0, 0, 0);
            aZ = __builtin_amdgcn_mfma_f32_16x16x32_bf16(h0[kc], WhhV[((2 + ch) * 16 + kc) * 64 + lane], aZ, 0, 0, 0);
            aNH = __builtin_amdgcn_mfma_f32_16x16x32_bf16(h0[kc], WhhV[((4 + ch) * 16 + kc) * 64 + lane], aNH, 0, 0, 0);
        }
    };

    float hreg[4];
#pragma unroll
    for (int i = 0; i < 4; ++i) hreg[i] = 0.0f;

    auto epi = [&](bf16* op) {
        bf16* stb = op + (size_t)(rowb + (lane >> 4) * 4) * Hh + colc;
        unsigned short us[4];
#pragma unroll
        for (int r = 0; r < 4; ++r) {
            float rg = sigmf(aR[r] + bi[0] + bh[0]);
            float zg = sigmf(aZ[r] + bi[1] + bh[1]);
            float ng = tanhfast(aNX[r] + bi[2] + rg * (aNH[r] + bh[2]));
            float hv = (1.0f - zg) * ng + zg * hreg[r];
            hreg[r] = hv;
            us[r] = __builtin_bit_cast(unsigned short, (bf16)hv);
        }
        ST_SC(stb, 0, us[0]);
        ST_SC(stb, 1024, us[1]);
        ST_SC(stb, 2048, us[2]);
        ST_SC(stb, 3072, us[3]);
    };

    // ---------- encoder ----------
    stage(WihE, Ee, 8, Wih);
    stage(WhhE, Hh, 16, Whh);
    load_bias(bIhE, bHhE);
    __syncthreads();

#pragma unroll 1
    for (int t = 0; t < Tt; ++t) {
        zacc();
        xp_phase(embP + (size_t)t * Bb * Ee);
        if (t > 0) hw_phase(((t - 1) & 1) ? hB : hA, (unsigned)t);
        epi((t & 1) ? hB : hA);
        signal((unsigned)(t + 1));  // seq 1..64
    }

    // ---------- hidden = h_enc + noise; switch to decoder weights ----------
    wait_all((unsigned)Tt);  // rh-domain peers done reading hA (enc step 63)
    {
        bf16* stb = hA + (size_t)(rowb + (lane >> 4) * 4) * Hh + colc;
        unsigned short us[4];
#pragma unroll
        for (int r = 0; r < 4; ++r) {
            int row = rowb + (lane >> 4) * 4 + r;
            float v = hreg[r] + noise[(size_t)row * Hh + colc];
            hreg[r] = v;
            us[r] = __builtin_bit_cast(unsigned short, (bf16)v);
        }
        ST_SC(stb, 0, us[0]);
        ST_SC(stb, 1024, us[1]);
        ST_SC(stb, 2048, us[2]);
        ST_SC(stb, 3072, us[3]);
    }
    __syncthreads();  // all waves of this block past their enc LDS reads
    stage(WihD, Ee, 8, Wih);
    stage(WhhD, Hh, 16, Whh);
    __syncthreads();  // decoder LDS staged before any wave's dec reads
    load_bias(bIhD, bHhD);
    signal((unsigned)(Tt + 1));  // seq 65: hA(+noise) visible

    // ---------- decoder; ys[t] doubles as the bf16 hidden chain ----------
#pragma unroll 1
    for (int t = 0; t < Tt; ++t) {
        zacc();
        if (t > 0) xp_phase(embF + (size_t)(t - 1) * Bb * Ee);
        hw_phase(t ? ys + (size_t)(t - 1) * Bb * Hh : hA, (unsigned)(Tt + 1 + t));  // seq 65+t
        epi(ys + (size_t)t * Bb * Hh);
        if (t < Tt - 1) signal((unsigned)(Tt + 2 + t));  // seq 66..128
    }
}

// ---------------- out = ys @ W_out + b_out; 64 rows/wave ----------------
__global__ __launch_bounds__(256) void k_out(const bf16* __restrict__ ys, const bf16* __restrict__ WT,
                                             const float* __restrict__ bias, float* __restrict__ out) {
    const int lane = threadIdx.x & 63, wv = threadIdx.x >> 6;
    const int m0w = blockIdx.x * 256 + wv * 64;
    const int c0 = blockIdx.y * 64;
    const int koff = (lane >> 4) * 8;
    f32x4 acc[4][4];
#pragma unroll
    for (int m = 0; m < 4; ++m)
#pragma unroll
        for (int s = 0; s < 4; ++s) acc[m][s] = f32x4{0.f, 0.f, 0.f, 0.f};

    const bf16* ap = ys + (size_t)(m0w + (lane & 15)) * Hh + koff;
#pragma unroll
    for (int kc = 0; kc < 16; ++kc) {
        bf16x8 a0 = *(const bf16x8*)(ap + kc * 32);
        bf16x8 a1 = *(const bf16x8*)(ap + 16 * Hh + kc * 32);
        bf16x8 a2 = *(const bf16x8*)(ap + 32 * Hh + kc * 32);
        bf16x8 a3 = *(const bf16x8*)(ap + 48 * Hh + kc * 32);
#pragma unroll
        for (int s = 0; s < 4; ++s) {
            bf16x8 b = *(const bf16x8*)(WT + (size_t)(c0 + s * 16 + (lane & 15)) * Hh + kc * 32 + koff);
            acc[0][s] = __builtin_amdgcn_mfma_f32_16x16x32_bf16(a0, b, acc[0][s], 0, 0, 0);
            acc[1][s] = __builtin_amdgcn_mfma_f32_16x16x32_bf16(a1, b, acc[1][s], 0, 0, 0);
            acc[2][s] = __builtin_amdgcn_mfma_f32_16x16x32_bf16(a2, b, acc[2][s], 0, 0, 0);
            acc[3][s] = __builtin_amdgcn_mfma_f32_16x16x32_bf16(a3, b, acc[3][s], 0, 0, 0);
        }
    }
#pragma unroll
    for (int m = 0; m < 4; ++m)
#pragma unroll
        for (int s = 0; s < 4; ++s) {
            int col = c0 + s * 16 + (lane & 15);
            float bv = bias[col];
#pragma unroll
            for (int r = 0; r < 4; ++r) {
                int row = m0w + m * 16 + (lane >> 4) * 4 + r;
                out[(size_t)row * Dd + col] = acc[m][s][r] + bv;
            }
        }
}

extern "C" void kernel_launch(void* const* d_in, const int* in_sizes, int n_in,
                              void* d_out, int out_size, void* d_ws, size_t ws_size,
                              hipStream_t stream) {
    const float* past = (const float*)d_in[0];
    const float* fut = (const float*)d_in[1];
    const float* noise = (const float*)d_in[2];
    const float* W_emb = (const float*)d_in[3];
    const float* b_emb = (const float*)d_in[4];
    const float* W_ih_enc = (const float*)d_in[5];
    const float* W_hh_enc = (const float*)d_in[6];
    const float* b_ih_enc = (const float*)d_in[7];
    const float* b_hh_enc = (const float*)d_in[8];
    const float* W_ih_dec = (const float*)d_in[9];
    const float* W_hh_dec = (const float*)d_in[10];
    const float* b_ih_dec = (const float*)d_in[11];
    const float* b_hh_dec = (const float*)d_in[12];
    const float* W_out = (const float*)d_in[13];
    const float* b_out = (const float*)d_in[14];
    float* out = (float*)d_out;

    char* w = (char*)d_ws;
    auto alloc = [&](size_t bytes) {
        char* p = w;
        w += (bytes + 255) & ~(size_t)255;
        return p;
    };
    bf16* embP = (bf16*)alloc((size_t)Tt * Bb * Ee * 2);
    bf16* embF = (bf16*)alloc((size_t)Tt * Bb * Ee * 2);
    bf16* ys = (bf16*)alloc((size_t)Tt * Bb * Hh * 2);
    bf16* hA = (bf16*)alloc((size_t)Bb * Hh * 2);
    bf16* hB = (bf16*)alloc((size_t)Bb * Hh * 2);
    bf16* WembT = (bf16*)alloc((size_t)Ee * Dd * 2);
    bf16* WihEncT = (bf16*)alloc((size_t)H3 * Ee * 2);
    bf16* WhhEncT = (bf16*)alloc((size_t)H3 * Hh * 2);
    bf16* WihDecT = (bf16*)alloc((size_t)H3 * Ee * 2);
    bf16* WhhDecT = (bf16*)alloc((size_t)H3 * Hh * 2);
    bf16* WoutT = (bf16*)alloc((size_t)Dd * Hh * 2);
    unsigned* flags = (unsigned*)alloc(16 * 4 * 32 * sizeof(unsigned));  // [im][rh][32]

    // weight prep (all six transposes fused)
    k_prep<<<9600, 256, 0, stream>>>(W_emb, W_ih_enc, W_hh_enc, W_ih_dec, W_hh_dec, W_out,
                                     WembT, WihEncT, WhhEncT, WihDecT, WhhDecT, WoutT);

    // embeddings (past + future fused)
    k_embed<<<dim3(Tt * Bb / 128, Ee / 64, 2), 256, 0, stream>>>(past, fut, WembT, b_emb, embP, embF);

    // reset sequence flags
    hipMemsetAsync(flags, 0, 16 * 4 * 32 * sizeof(unsigned), stream);

    // cooperative persistent recurrent kernel
    void* args[] = {(void*)&embP, (void*)&embF, (void*)&noise,
                    (void*)&WihEncT, (void*)&WhhEncT, (void*)&b_ih_enc, (void*)&b_hh_enc,
                    (void*)&WihDecT, (void*)&WhhDecT, (void*)&b_ih_dec, (void*)&b_hh_dec,
                    (void*)&hA, (void*)&hB, (void*)&ys, (void*)&flags};
    hipLaunchCooperativeKernel((const void*)k_gru_all, dim3(256), dim3(512), args, 0, stream);

    // output projection
    k_out<<<dim3(Tt * Bb / 256, Dd / 64), 256, 0, stream>>>(ys, WoutT, b_out, out);
}